// Round 4
// baseline (646.603 us; speedup 1.0000x reference)
//
#include <hip/hip_runtime.h>
#include <cstdint>
#include <cstddef>

// Problem constants
#define B_        2
#define LSEQ      4096
#define DMODEL    2048
#define NH        32
#define PDIM      64
#define NSTATE    128
#define KCONV     4
#define INTER     2048       // NH*PDIM
#define CONV_DIM  2304       // INTER + 2*NSTATE
#define HBCDT     2336       // CONV_DIM + NH
#define HBCDT_PAD 2432       // hbcdt row stride (19*128), unchanged
#define WH_ROWS   2560       // W_h padded rows for 256-wide GEMM tiles
#define ROWS      (B_*LSEQ)  // 8192
#define NC        32         // sequence chunks for the scan
#define CLEN      (LSEQ/NC)  // 128  (= Q)

typedef unsigned short ushort_t;
typedef short bf16x8 __attribute__((ext_vector_type(8)));
typedef float f32x4 __attribute__((ext_vector_type(4)));

__device__ __forceinline__ float siluf(float x) {
  return x / (1.0f + __expf(-x));
}
__device__ __forceinline__ float bf2f(ushort_t u) {
  union { unsigned int i; float f; } v; v.i = ((unsigned int)u) << 16; return v.f;
}
__device__ __forceinline__ ushort_t f2bf(float f) {
  union { float f; unsigned int i; } v; v.f = f;
  unsigned int r = v.i + 0x7fff + ((v.i >> 16) & 1);   // RNE
  return (ushort_t)(r >> 16);
}
__device__ __forceinline__ void async16(const void* g, void* l) {
  __builtin_amdgcn_global_load_lds(
      (const __attribute__((address_space(1))) unsigned int*)g,
      (__attribute__((address_space(3))) unsigned int*)l, 16, 0, 0);
}

// ---------------------------------------------------------------------------
// fp32 -> bf16 conversions
// ---------------------------------------------------------------------------
__global__ __launch_bounds__(256) void cvt_f32_bf16(
    const float* __restrict__ src, ushort_t* __restrict__ dst, int n) {
  const int i = (blockIdx.x * 256 + threadIdx.x) * 4;
  if (i >= n) return;
  float4 v = *(const float4*)(src + i);
  ushort4 o; o.x = f2bf(v.x); o.y = f2bf(v.y); o.z = f2bf(v.z); o.w = f2bf(v.w);
  *(ushort4*)(dst + i) = o;
}

// W_in rows [INTER, INTER+HBCDT) -> bf16 padded to WH_ROWS rows (zeros)
__global__ __launch_bounds__(256) void cvt_Wh(
    const float* __restrict__ W_in, ushort_t* __restrict__ dst) {
  const int i = (blockIdx.x * 256 + threadIdx.x) * 4;
  if (i >= WH_ROWS * DMODEL) return;
  const int r = i / DMODEL, c = i % DMODEL;
  ushort4 o;
  if (r < HBCDT) {
    float4 v = *(const float4*)(W_in + (size_t)(INTER + r) * DMODEL + c);
    o.x = f2bf(v.x); o.y = f2bf(v.y); o.z = f2bf(v.z); o.w = f2bf(v.w);
  } else {
    o.x = 0; o.y = 0; o.z = 0; o.w = 0;
  }
  *(ushort4*)(dst + i) = o;
}

// ---------------------------------------------------------------------------
// 256x256 8-phase bf16 NT GEMM with COUNTED vmcnt (T4 proper, m218/m201).
// C[m,n] = sum_k A[m,k]*B[n,k], K = 2048 fixed, BK = 64, 8 waves (2M x 4N).
// Pipeline: tile j's 8 stage loads are issued at the TAIL of tile j-2
// (immediately after that phase's lgkmcnt(0) proves the target buffer's
// ds_reads retired), and the tail waits vmcnt(8) -- i.e. only for tile
// j-1's loads, keeping tile j's 8 in flight. No vmcnt(0) in the main loop;
// single terminal drain when the last tile has no successor.
// T2 swizzle: LDS granule16 g' = g ^ (row&7), staged via pre-swizzled
// global source (linear LDS dest), read with the same XOR. T5 setprio.
// T1 XCD-aware bid swizzle (NWG % 8 == 0 for all launches).
// ---------------------------------------------------------------------------
#define STAGE_A(CN, H, KTT) do {                                              \
    async16(Ast + (size_t)((H) * 128) * 2048 + (KTT) * 64,                    \
            smem_ + (CN) + (H) * 16384 + wave * 1024);                        \
    async16(Ast + (size_t)((H) * 128 + 64) * 2048 + (KTT) * 64,               \
            smem_ + (CN) + (H) * 16384 + 8192 + wave * 1024);                 \
  } while (0)

#define STAGE_B(CN, H, KTT) do {                                              \
    async16(Bst + (size_t)((H) * 128) * 2048 + (KTT) * 64,                    \
            smem_ + 65536 + (CN) + (H) * 16384 + wave * 1024);                \
    async16(Bst + (size_t)((H) * 128 + 64) * 2048 + (KTT) * 64,               \
            smem_ + 65536 + (CN) + (H) * 16384 + 8192 + wave * 1024);         \
  } while (0)

#define LDA(DST, CB, MH) do {                                                 \
    const char* ab_ = smem_ + (CB) + aro;                                     \
    _Pragma("unroll") for (int mi_ = 0; mi_ < 4; ++mi_) {                     \
      DST[mi_][0] = *(const bf16x8*)(ab_ + (MH) * 8192 + mi_ * 2048 + g0);    \
      DST[mi_][1] = *(const bf16x8*)(ab_ + (MH) * 8192 + mi_ * 2048 + g1);    \
    }                                                                         \
  } while (0)

#define LDB(DST, CB, NHH) do {                                                \
    const char* bb_ = smem_ + 65536 + (CB) + bro;                             \
    _Pragma("unroll") for (int ni_ = 0; ni_ < 2; ++ni_) {                     \
      DST[ni_][0] = *(const bf16x8*)(bb_ + (NHH) * 4096 + ni_ * 2048 + g0);   \
      DST[ni_][1] = *(const bf16x8*)(bb_ + (NHH) * 4096 + ni_ * 2048 + g1);   \
    }                                                                         \
  } while (0)

#define MFMAQ(MH, NHH, AF, BF)                                                \
  _Pragma("unroll") for (int mi_ = 0; mi_ < 4; ++mi_)                         \
  _Pragma("unroll") for (int ni_ = 0; ni_ < 2; ++ni_) {                       \
    f32x4& c_ = acc[(MH) * 4 + mi_][(NHH) * 2 + ni_];                         \
    c_ = __builtin_amdgcn_mfma_f32_16x16x32_bf16(AF[mi_][0], BF[ni_][0], c_, 0, 0, 0); \
    c_ = __builtin_amdgcn_mfma_f32_16x16x32_bf16(AF[mi_][1], BF[ni_][1], c_, 0, 0, 0); \
  }

#define PH(X) do {                                                            \
    __builtin_amdgcn_s_barrier();                                             \
    asm volatile("s_waitcnt lgkmcnt(0)" ::: "memory");                        \
    __builtin_amdgcn_sched_barrier(0);                                        \
    __builtin_amdgcn_s_setprio(1);                                            \
    X;                                                                        \
    __builtin_amdgcn_s_setprio(0);                                            \
    __builtin_amdgcn_s_barrier();                                             \
  } while (0)

// Tail of a K-tile group: after lgkmcnt(0) the current buffer's ds_reads are
// retired, so it is legal to re-stage it with tile KTT. Counted wait leaves
// the 8 just-issued loads in flight; waits only for the previous tile's 8.
#define GROUP_TAIL_CNT(X, DOSTAGE, CN, KTT) do {                              \
    __builtin_amdgcn_s_barrier();                                             \
    asm volatile("s_waitcnt lgkmcnt(0)" ::: "memory");                        \
    __builtin_amdgcn_sched_barrier(0);                                        \
    __builtin_amdgcn_s_setprio(1);                                            \
    X;                                                                        \
    __builtin_amdgcn_s_setprio(0);                                            \
    if (DOSTAGE) {                                                            \
      STAGE_A(CN, 0, KTT); STAGE_A(CN, 1, KTT);                               \
      STAGE_B(CN, 0, KTT); STAGE_B(CN, 1, KTT);                               \
      asm volatile("s_waitcnt vmcnt(8)" ::: "memory");                        \
    } else {                                                                  \
      asm volatile("s_waitcnt vmcnt(0)" ::: "memory");                        \
    }                                                                         \
    __builtin_amdgcn_s_barrier();                                             \
  } while (0)

template <bool OUT_BF16, int NTN, int NVALID, int LDC>
__global__ __launch_bounds__(512, 2) void gemm256_nt(
    const ushort_t* __restrict__ A, const ushort_t* __restrict__ B,
    void* __restrict__ C) {
  __shared__ __align__(16) char smem_[131072];
  const int t    = threadIdx.x;
  const int lane = t & 63;
  const int wave = t >> 6;
  const int wm   = wave >> 2;   // 0..1  (M half of the tile)
  const int wn   = wave & 3;    // 0..3  (N quarter)

  // XCD-aware tile swizzle (NWG % 8 == 0 always here -> bijective)
  constexpr int NWG = NTN * 32;
  int bid = blockIdx.y * NTN + blockIdx.x;
  bid = (bid & 7) * (NWG >> 3) + (bid >> 3);
  const int m0 = (bid / NTN) * 256;
  const int n0 = (bid % NTN) * 256;

  // staging: thread covers row (wave*8 + lane>>3), granule (lane&7)^(lane>>3)
  const int srow = wave * 8 + (lane >> 3);
  const int scol = ((lane & 7) ^ (lane >> 3)) * 8;
  const ushort_t* Ast = A + (size_t)(m0 + srow) * 2048 + scol;
  const ushort_t* Bst = B + (size_t)(n0 + srow) * 2048 + scol;

  // fragment-read bases; row&7 == lane&7 for all fragment rows
  const int aro = (wm * 128 + (lane & 15)) * 128;
  const int bro = (wn * 64 + (lane & 15)) * 128;
  const int g0  = ((lane >> 4) ^ (lane & 7)) * 16;
  const int g1  = (((lane >> 4) + 4) ^ (lane & 7)) * 16;

  f32x4 acc[8][4];
#pragma unroll
  for (int i = 0; i < 8; ++i)
#pragma unroll
    for (int j = 0; j < 4; ++j) {
      f32x4 z = {0.f, 0.f, 0.f, 0.f};
      acc[i][j] = z;
    }
  bf16x8 af[4][2], bq0[2][2], bq1[2][2];

  // prologue: stage tile 0 -> buf0, tile 1 -> buf1; wait only for tile 0
  STAGE_A(0, 0, 0); STAGE_A(0, 1, 0);
  STAGE_B(0, 0, 0); STAGE_B(0, 1, 0);
  STAGE_A(32768, 0, 1); STAGE_A(32768, 1, 1);
  STAGE_B(32768, 0, 1); STAGE_B(32768, 1, 1);
  asm volatile("s_waitcnt vmcnt(8)" ::: "memory");
  __builtin_amdgcn_s_barrier();

  constexpr int NT = 2048 / 64;  // 32 K-tiles
  for (int kt = 0; kt < NT; kt += 2) {
    // ---- group A: compute tile kt from buf0; tail stages kt+2 -> buf0 ----
    LDA(af, 0, 0); LDB(bq0, 0, 0);
    PH(MFMAQ(0, 0, af, bq0));
    LDB(bq1, 0, 1);
    PH(MFMAQ(0, 1, af, bq1));
    LDA(af, 0, 1); LDB(bq0, 0, 0);
    PH(MFMAQ(1, 0, af, bq0));
    LDB(bq1, 0, 1);
    GROUP_TAIL_CNT(MFMAQ(1, 1, af, bq1), (kt + 2) < NT, 0, kt + 2);
    // ---- group B: compute tile kt+1 from buf1; tail stages kt+3 -> buf1 ----
    LDA(af, 32768, 0); LDB(bq0, 32768, 0);
    PH(MFMAQ(0, 0, af, bq0));
    LDB(bq1, 32768, 1);
    PH(MFMAQ(0, 1, af, bq1));
    LDA(af, 32768, 1); LDB(bq0, 32768, 0);
    PH(MFMAQ(1, 0, af, bq0));
    LDB(bq1, 32768, 1);
    GROUP_TAIL_CNT(MFMAQ(1, 1, af, bq1), (kt + 3) < NT, 32768, kt + 3);
  }

  // epilogue: C/D mapping col=lane&15, row=(lane>>4)*4+reg
  const int mb = m0 + wm * 128 + (lane >> 4) * 4;
  const int nb = n0 + wn * 64 + (lane & 15);
#pragma unroll
  for (int mq = 0; mq < 8; ++mq)
#pragma unroll
    for (int nq = 0; nq < 4; ++nq)
#pragma unroll
      for (int r = 0; r < 4; ++r) {
        const int m = mb + mq * 16 + r;
        const int n = nb + nq * 16;
        if (n < NVALID) {
          if (OUT_BF16)
            ((ushort_t*)C)[(size_t)m * LDC + n] = f2bf(acc[mq][nq][r]);
          else
            ((float*)C)[(size_t)m * LDC + n] = acc[mq][nq][r];
        }
      }
}

// ---------------------------------------------------------------------------
// Depthwise causal conv1d (K=4) + bias + SiLU. Input hbcdt bf16 (ld 2432),
// output convo bf16 (ld 2304). Additionally writes the B section (c in
// [INTER, INTER+NSTATE)) transposed: BT_g[b][chunk][n][s_local] for the
// MFMA scan-state kernel (G=1: B is head-shared).
// ---------------------------------------------------------------------------
__global__ __launch_bounds__(256) void conv_silu_kernel(
    const ushort_t* __restrict__ hbcdt, const float* __restrict__ conv_w,
    const float* __restrict__ conv_b, ushort_t* __restrict__ convo,
    ushort_t* __restrict__ BT_g) {
  const int idx = blockIdx.x * 256 + threadIdx.x;
  if (idx >= ROWS * CONV_DIM) return;
  const int c   = idx % CONV_DIM;
  const int row = idx / CONV_DIM;
  const int l   = row & (LSEQ - 1);
  float acc = conv_b[c];
  const float* w = conv_w + c * KCONV;
#pragma unroll
  for (int k = 0; k < KCONV; ++k) {
    const int tt = l + k - (KCONV - 1);
    if (tt >= 0)
      acc = fmaf(bf2f(hbcdt[(size_t)(row + k - (KCONV - 1)) * HBCDT_PAD + c]), w[k], acc);
  }
  const ushort_t v = f2bf(siluf(acc));
  convo[idx] = v;
  if (c >= INTER && c < INTER + NSTATE) {
    const int n   = c - INTER;
    const int bb  = row >> 12;        // / LSEQ
    const int cch = l >> 7;           // / CLEN
    const int sl  = l & (CLEN - 1);
    BT_g[(((size_t)bb * NC + cch) * NSTATE + n) * CLEN + sl] = v;
  }
}

// ---------------------------------------------------------------------------
// dt = softplus(dt_raw + dt_bias)
// ---------------------------------------------------------------------------
__global__ __launch_bounds__(256) void dtprep_kernel(
    const ushort_t* __restrict__ hbcdt, const float* __restrict__ dt_bias,
    float* __restrict__ dt_s) {
  const int idx = blockIdx.x * 256 + threadIdx.x;
  if (idx >= ROWS * NH) return;
  const int h   = idx & (NH - 1);
  const int row = idx >> 5;
  float x = bf2f(hbcdt[(size_t)row * HBCDT_PAD + CONV_DIM + h]) + dt_bias[h];
  dt_s[idx] = (x > 20.f) ? x : log1pf(__expf(x));
}

// ---------------------------------------------------------------------------
// Chunked scan, pass 1 (MFMA form): per (b,h,c),
//   La = cumsum(-exp(A_log[h])*dt);  wgt[s] = dt_s * exp(La_end - La_s)
//   S_loc[p][n] = sum_s (x_s[p]*wgt[s]) * B_s[n]   -> NT MFMA, K=s=128
//   chunkA = exp(La_end)
// Grid: B*NH*NC = 2048 blocks x 256 thr (4 waves; wave w -> p rows w*16..+16).
// ---------------------------------------------------------------------------
#define XLD 272   // Xw^T row stride bytes (128*2 + 16 pad -> 2-way conflicts only)
__global__ __launch_bounds__(256) void scan_state_kernel(
    const ushort_t* __restrict__ convo, const float* __restrict__ dt_s,
    const float* __restrict__ A_log, const ushort_t* __restrict__ BT_g,
    ushort_t* __restrict__ Sbuf, float* __restrict__ chunkA) {
  __shared__ __align__(16) char XwT[64 * XLD];   // [p][s] bf16, weighted
  __shared__ float dt_sh[CLEN];
  __shared__ float wgt[CLEN];

  const int blk = blockIdx.x;
  const int c   = blk & (NC - 1);
  const int h   = (blk >> 5) & 31;
  const int b   = blk >> 10;
  const int t   = threadIdx.x;
  const int lane = t & 63;
  const int wave = t >> 6;
  const size_t crow = (size_t)(b * LSEQ + c * CLEN);

  if (t < CLEN) dt_sh[t] = dt_s[(crow + t) * NH + h];
  __syncthreads();

  if (wave == 0) {
    const float a = __expf(A_log[h]);
    float v0 = -a * dt_sh[lane];
    float v1 = -a * dt_sh[lane + 64];
#pragma unroll
    for (int off = 1; off < 64; off <<= 1) {
      float u0 = __shfl_up(v0, off);
      float u1 = __shfl_up(v1, off);
      if (lane >= off) { v0 += u0; v1 += u1; }
    }
    const float tot0 = __shfl(v0, 63);
    const float La0  = v0;
    const float La1  = v1 + tot0;
    const float Lend = __shfl(v1, 63) + tot0;
    wgt[lane]      = dt_sh[lane]      * __expf(Lend - La0);
    wgt[lane + 64] = dt_sh[lane + 64] * __expf(Lend - La1);
    if (lane == 0) chunkA[(b * NH + h) * NC + c] = __expf(Lend);
  }
  __syncthreads();

  // stage weighted Xw^T: thread lane = p, wave covers t in [wave*32, +32)
  {
    const int p = lane;
    const int xcol = h * PDIM + p;
#pragma unroll
    for (int oct = 0; oct < 4; ++oct) {
      const int t0 = wave * 32 + oct * 8;
      unsigned int pk[4];
#pragma unroll
      for (int e = 0; e < 4; ++e) {
        const float f0 = bf2f(convo[(crow + t0 + 2*e)     * CONV_DIM + xcol]) * wgt[t0 + 2*e];
        const float f1 = bf2f(convo[(crow + t0 + 2*e + 1) * CONV_DIM + xcol]) * wgt[t0 + 2*e + 1];
        pk[e] = (unsigned int)f2bf(f0) | ((unsigned int)f2bf(f1) << 16);
      }
      *(uint4*)(XwT + p * XLD + t0 * 2) = make_uint4(pk[0], pk[1], pk[2], pk[3]);
    }
  }
  __syncthreads();

  // MFMA: S_loc[p][n], A = Xw^T (LDS), B = BT_g (global, L2-hot)
  f32x4 acc[8];
#pragma unroll
  for (int j = 0; j < 8; ++j) {
    f32x4 z = {0.f, 0.f, 0.f, 0.f};
    acc[j] = z;
  }
  const int rowA = wave * 16 + (lane & 15);
  const int koff = (lane >> 4) * 8;
  const ushort_t* Bt = BT_g + ((size_t)b * NC + c) * NSTATE * CLEN;
#pragma unroll
  for (int k0 = 0; k0 < 4; ++k0) {
    bf16x8 af = *(const bf16x8*)(XwT + rowA * XLD + (k0 * 32 + koff) * 2);
#pragma unroll
    for (int j = 0; j < 8; ++j) {
      bf16x8 bfx = *(const bf16x8*)(Bt + (size_t)(j * 16 + (lane & 15)) * CLEN + k0 * 32 + koff);
      acc[j] = __builtin_amdgcn_mfma_f32_16x16x32_bf16(af, bfx, acc[j], 0, 0, 0);
    }
  }

  ushort_t* Sb = Sbuf + (((size_t)b * NC + c) * NH + h) * (PDIM * NSTATE);
  const int prow = wave * 16 + (lane >> 4) * 4;
  const int ncol = lane & 15;
#pragma unroll
  for (int j = 0; j < 8; ++j)
#pragma unroll
    for (int r = 0; r < 4; ++r)
      Sb[(size_t)(prow + r) * NSTATE + j * 16 + ncol] = f2bf(acc[j][r]);
}

// ---------------------------------------------------------------------------
// Chunked scan, pass 2: in-place serial combine over chunks.
// ---------------------------------------------------------------------------
__global__ __launch_bounds__(256) void state_combine_kernel(
    ushort_t* __restrict__ Sbuf, const float* __restrict__ chunkA) {
  const int idx = blockIdx.x * 256 + threadIdx.x;
  const int nq = idx & 31;
  const int p  = (idx >> 5) & 63;
  const int h  = (idx >> 11) & 31;
  const int b  = (idx >> 16) & 1;
  const float* ca = chunkA + (b * NH + h) * NC;

  float s0 = 0.f, s1 = 0.f, s2 = 0.f, s3 = 0.f;
#pragma unroll 4
  for (int c = 0; c < NC; ++c) {
    const size_t off = ((((size_t)b * NC + c) * NH + h) * PDIM + p) * NSTATE + nq * 4;
    ushort4 loc = *(const ushort4*)(Sbuf + off);
    ushort4 o;
    o.x = f2bf(s0); o.y = f2bf(s1); o.z = f2bf(s2); o.w = f2bf(s3);
    *(ushort4*)(Sbuf + off) = o;                 // Sin for chunk c
    const float a = ca[c];
    s0 = fmaf(a, s0, bf2f(loc.x));
    s1 = fmaf(a, s1, bf2f(loc.y));
    s2 = fmaf(a, s2, bf2f(loc.z));
    s3 = fmaf(a, s3, bf2f(loc.w));
  }
}

// ---------------------------------------------------------------------------
// SSD Y-kernel: per (b,h,c) chunk of Q=128,
//   La[t] = cumsum(-exp(A_log[h])*dt) over chunk
//   G = C @ B^T;  W[t,s] = (t>=s) ? G*dt[s]*exp(La[t]-La[s]) : 0  -> LDS bf16
//   Y = exp(La[t]) o (C @ Sin^T) + W @ X + D*x
// Grid: B*NH*NC = 2048 blocks x 256 thr (4 waves).
// ---------------------------------------------------------------------------
#define WLD 272   // W row stride bytes (128*2 + 16 pad -> 2-way bank conflicts only)
__global__ __launch_bounds__(256) void ssd_y_kernel(
    const ushort_t* __restrict__ convo, const float* __restrict__ dt_s,
    const float* __restrict__ A_log, const float* __restrict__ D_param,
    const ushort_t* __restrict__ Sbuf, ushort_t* __restrict__ ybuf) {
  __shared__ __align__(16) char XT[64 * 256];     // [p][t^sw] bf16
  __shared__ __align__(16) char Wsh[128 * WLD];   // [t][s] bf16, padded rows
  __shared__ float dt_sh[CLEN];
  __shared__ float La[CLEN];

  const int blk = blockIdx.x;
  const int c   = blk & (NC - 1);
  const int h   = (blk >> 5) & 31;
  const int b   = blk >> 10;
  const int t   = threadIdx.x;
  const int lane = t & 63;
  const int wave = t >> 6;

  const size_t crow = (size_t)(b * LSEQ + c * CLEN);

  // ---- stage X transposed into LDS (XOR swizzle on t within 64-t octets) ----
  {
    const int p = lane;
    const int xcol = h * PDIM + p;
#pragma unroll
    for (int oct = 0; oct < 4; ++oct) {
      const int tl0 = wave * 32 + oct * 8;
      unsigned int pk[4];
#pragma unroll
      for (int e = 0; e < 4; ++e) {
        ushort_t v0 = convo[(crow + tl0 + 2 * e) * CONV_DIM + xcol];
        ushort_t v1 = convo[(crow + tl0 + 2 * e + 1) * CONV_DIM + xcol];
        pk[e] = (unsigned int)v0 | ((unsigned int)v1 << 16);
      }
      const int tsw = tl0 ^ ((p & 7) << 3);
      *(uint4*)(XT + p * 256 + tsw * 2) = make_uint4(pk[0], pk[1], pk[2], pk[3]);
    }
  }
  // ---- stage dt for chunk ----
  if (t < CLEN) dt_sh[t] = dt_s[(crow + t) * NH + h];
  __syncthreads();

  // ---- wave 0: inclusive prefix sum of log(dA) = -a*dt ----
  if (wave == 0) {
    const float a = __expf(A_log[h]);
    float v0 = -a * dt_sh[lane];
    float v1 = -a * dt_sh[lane + 64];
#pragma unroll
    for (int off = 1; off < 64; off <<= 1) {
      float u0 = __shfl_up(v0, off);
      float u1 = __shfl_up(v1, off);
      if (lane >= off) { v0 += u0; v1 += u1; }
    }
    const float tot0 = __shfl(v0, 63);
    La[lane]      = v0;
    La[lane + 64] = v1 + tot0;
  }
  __syncthreads();

  // ---- phase 1: G = C @ B^T (per-wave 64x64 tile), then W -> LDS ----
  const int wt = wave & 1;
  const int ws = wave >> 1;
  const bool active = !(wt == 0 && ws == 1);   // strictly-upper tile is all zero

  f32x4 g[4][4];
#pragma unroll
  for (int i = 0; i < 4; ++i)
#pragma unroll
    for (int j = 0; j < 4; ++j) {
      f32x4 z = {0.f, 0.f, 0.f, 0.f};
      g[i][j] = z;
    }

  if (active) {
    for (int k0 = 0; k0 < 4; ++k0) {
      const int koct = k0 * 32 + (lane >> 4) * 8;
      bf16x8 cf[4], bfg[4];
#pragma unroll
      for (int i = 0; i < 4; ++i) {
        const int tg = wt * 64 + i * 16 + (lane & 15);
        cf[i] = *(const bf16x8*)(convo + (crow + tg) * CONV_DIM + INTER + NSTATE + koct);
        const int sg = ws * 64 + i * 16 + (lane & 15);
        bfg[i] = *(const bf16x8*)(convo + (crow + sg) * CONV_DIM + INTER + koct);
      }
#pragma unroll
      for (int i = 0; i < 4; ++i)
#pragma unroll
        for (int j = 0; j < 4; ++j)
          g[i][j] = __builtin_amdgcn_mfma_f32_16x16x32_bf16(cf[i], bfg[j], g[i][j], 0, 0, 0);
    }
  }
#pragma unroll
  for (int i = 0; i < 4; ++i) {
    const int tbase = wt * 64 + i * 16 + ((lane >> 4) << 2);
    float Lat[4];
#pragma unroll
    for (int r = 0; r < 4; ++r) Lat[r] = La[tbase + r];
#pragma unroll
    for (int j = 0; j < 4; ++j) {
      const int sl  = ws * 64 + j * 16 + (lane & 15);
      const float Las = La[sl];
      const float dts = dt_sh[sl];
#pragma unroll
      for (int r = 0; r < 4; ++r) {
        const int tl = tbase + r;
        float val = 0.f;
        if (active && tl >= sl)
          val = g[i][j][r] * dts * __expf(Lat[r] - Las);
        *(ushort_t*)(Wsh + tl * WLD + sl * 2) = f2bf(val);
      }
    }
  }
  __syncthreads();

  // ---- phase 2: Y = exp(La) o (C @ Sin^T) + W @ X ----
  const int yt = wave & 1;        // t-half
  const int yp = wave >> 1;       // p-half (32 p's per wave)
  f32x4 acc[4][2];
#pragma unroll
  for (int i = 0; i < 4; ++i)
#pragma unroll
    for (int j = 0; j < 2; ++j) {
      f32x4 z = {0.f, 0.f, 0.f, 0.f};
      acc[i][j] = z;
    }

  const ushort_t* Sb = Sbuf + (((size_t)b * NC + c) * NH + h) * PDIM * NSTATE;

  // Yinter: C @ Sin^T  (K = N = 128)
  for (int k0 = 0; k0 < 4; ++k0) {
    const int koct = k0 * 32 + (lane >> 4) * 8;
    bf16x8 af[4], sf[2];
#pragma unroll
    for (int i = 0; i < 4; ++i) {
      const int tg = yt * 64 + i * 16 + (lane & 15);
      af[i] = *(const bf16x8*)(convo + (crow + tg) * CONV_DIM + INTER + NSTATE + koct);
    }
#pragma unroll
    for (int j = 0; j < 2; ++j) {
      const int pr = yp * 32 + j * 16 + (lane & 15);
      sf[j] = *(const bf16x8*)(Sb + pr * NSTATE + koct);
    }
#pragma unroll
    for (int i = 0; i < 4; ++i)
#pragma unroll
      for (int j = 0; j < 2; ++j)
        acc[i][j] = __builtin_amdgcn_mfma_f32_16x16x32_bf16(af[i], sf[j], acc[i][j], 0, 0, 0);
  }
  // scale by exp(La[t]) in fp32
#pragma unroll
  for (int i = 0; i < 4; ++i) {
    const int tbase = yt * 64 + i * 16 + ((lane >> 4) << 2);
#pragma unroll
    for (int r = 0; r < 4; ++r) {
      const float e = __expf(La[tbase + r]);
#pragma unroll
      for (int j = 0; j < 2; ++j) acc[i][j][r] *= e;
    }
  }
  // Yintra: W @ X  (K = Q = 128; A from Wsh, B from XT)
  for (int k0 = 0; k0 < 4; ++k0) {
    const int koct = k0 * 32 + (lane >> 4) * 8;
    bf16x8 wf[4], xf[2];
#pragma unroll
    for (int i = 0; i < 4; ++i) {
      const int tl = yt * 64 + i * 16 + (lane & 15);
      wf[i] = *(const bf16x8*)(Wsh + tl * WLD + koct * 2);
    }
#pragma unroll
    for (int j = 0; j < 2; ++j) {
      const int pr  = yp * 32 + j * 16 + (lane & 15);
      const int tsw = koct ^ ((pr & 7) << 3);
      xf[j] = *(const bf16x8*)(XT + pr * 256 + tsw * 2);
    }
#pragma unroll
    for (int i = 0; i < 4; ++i)
#pragma unroll
      for (int j = 0; j < 2; ++j)
        acc[i][j] = __builtin_amdgcn_mfma_f32_16x16x32_bf16(wf[i], xf[j], acc[i][j], 0, 0, 0);
  }

  // ---- epilogue: + D*x, write y ----
  const float Dh = D_param[h];
#pragma unroll
  for (int i = 0; i < 4; ++i) {
    const int tbase = yt * 64 + i * 16 + ((lane >> 4) << 2);
#pragma unroll
    for (int j = 0; j < 2; ++j) {
      const int pr = yp * 32 + j * 16 + (lane & 15);
#pragma unroll
      for (int r = 0; r < 4; ++r) {
        const int tl  = tbase + r;
        const int tsw = tl ^ ((pr & 7) << 3);
        const float x = bf2f(*(const ushort_t*)(XT + pr * 256 + tsw * 2));
        ybuf[(crow + tl) * INTER + h * PDIM + pr] = f2bf(acc[i][j][r] + Dh * x);
      }
    }
  }
}

// ---------------------------------------------------------------------------
// Gated RMSNorm (bf16 in/out, in-place on y).
// ---------------------------------------------------------------------------
__global__ __launch_bounds__(256) void gated_rmsnorm_kernel(
    ushort_t* __restrict__ y, const ushort_t* __restrict__ gate,
    const float* __restrict__ norm_w) {
  const int row = blockIdx.x;
  ushort_t* yr = y + (size_t)row * INTER;
  const ushort_t* gr = gate + (size_t)row * INTER;
  const int t  = threadIdx.x;
  const int i0 = t * 8;

  ushort4 ya = *(const ushort4*)(yr + i0);
  ushort4 yb = *(const ushort4*)(yr + i0 + 4);
  ushort4 ga = *(const ushort4*)(gr + i0);
  ushort4 gb = *(const ushort4*)(gr + i0 + 4);

  float g[8];
  g[0] = bf2f(ya.x) * siluf(bf2f(ga.x));
  g[1] = bf2f(ya.y) * siluf(bf2f(ga.y));
  g[2] = bf2f(ya.z) * siluf(bf2f(ga.z));
  g[3] = bf2f(ya.w) * siluf(bf2f(ga.w));
  g[4] = bf2f(yb.x) * siluf(bf2f(gb.x));
  g[5] = bf2f(yb.y) * siluf(bf2f(gb.y));
  g[6] = bf2f(yb.z) * siluf(bf2f(gb.z));
  g[7] = bf2f(yb.w) * siluf(bf2f(gb.w));

  float ss = 0.f;
#pragma unroll
  for (int i = 0; i < 8; ++i) ss += g[i] * g[i];

  ss += __shfl_xor(ss, 32);
  ss += __shfl_xor(ss, 16);
  ss += __shfl_xor(ss, 8);
  ss += __shfl_xor(ss, 4);
  ss += __shfl_xor(ss, 2);
  ss += __shfl_xor(ss, 1);

  __shared__ float red[4];
  if ((t & 63) == 0) red[t >> 6] = ss;
  __syncthreads();
  const float tot = red[0] + red[1] + red[2] + red[3];
  const float scale = rsqrtf(tot * (1.0f / INTER) + 1e-5f);

  ushort4 o0, o1;
  o0.x = f2bf(g[0] * scale * norm_w[i0 + 0]);
  o0.y = f2bf(g[1] * scale * norm_w[i0 + 1]);
  o0.z = f2bf(g[2] * scale * norm_w[i0 + 2]);
  o0.w = f2bf(g[3] * scale * norm_w[i0 + 3]);
  o1.x = f2bf(g[4] * scale * norm_w[i0 + 4]);
  o1.y = f2bf(g[5] * scale * norm_w[i0 + 5]);
  o1.z = f2bf(g[6] * scale * norm_w[i0 + 6]);
  o1.w = f2bf(g[7] * scale * norm_w[i0 + 7]);
  *(ushort4*)(yr + i0)     = o0;
  *(ushort4*)(yr + i0 + 4) = o1;
}

// ---------------------------------------------------------------------------
// Workspace (~108 MB): hbcdt_bf(39.8, aliased by ybuf) | convo(37.7) |
// dt_s(1) | Wh_bf(10.5, 2560 rows) | Wg_bf(8.4) | Wout_bf(8.4) | chunkA(8KB) |
// BT_g(2). d_out scratch: [0,33.5MB) gate_bf; [33.5,67MB) hs_bf -> Sbuf.
// ---------------------------------------------------------------------------
extern "C" void kernel_launch(void* const* d_in, const int* in_sizes, int n_in,
                              void* d_out, int out_size, void* d_ws, size_t ws_size,
                              hipStream_t stream) {
  const float* hs      = (const float*)d_in[0];
  const float* W_in    = (const float*)d_in[1];
  const float* conv_w  = (const float*)d_in[2];
  const float* conv_b  = (const float*)d_in[3];
  const float* dt_bias = (const float*)d_in[4];
  const float* A_log   = (const float*)d_in[5];
  const float* D_param = (const float*)d_in[6];
  const float* norm_w  = (const float*)d_in[7];
  const float* W_out   = (const float*)d_in[8];
  float* out = (float*)d_out;

  char* ws = (char*)d_ws;
  size_t off = 0;
  ushort_t* hbcdt_bf = (ushort_t*)(ws + off); off += (size_t)ROWS * HBCDT_PAD * 2;
  ushort_t* convo    = (ushort_t*)(ws + off); off += (size_t)ROWS * CONV_DIM * 2;
  float*    dt_s     = (float*)(ws + off);    off += (size_t)ROWS * NH * 4;
  ushort_t* Wh_bf    = (ushort_t*)(ws + off); off += (size_t)WH_ROWS * DMODEL * 2;
  ushort_t* Wg_bf    = (ushort_t*)(ws + off); off += (size_t)DMODEL * DMODEL * 2;
  ushort_t* Wout_bf  = (ushort_t*)(ws + off); off += (size_t)DMODEL * DMODEL * 2;
  float*    chunkA   = (float*)(ws + off);    off += (size_t)B_ * NH * NC * 4;
  ushort_t* BT_g     = (ushort_t*)(ws + off); off += (size_t)B_ * NC * NSTATE * CLEN * 2;
  ushort_t* ybuf_bf  = hbcdt_bf;                       // alias (hBC_dt dead)

  char* outc = (char*)d_out;
  ushort_t* gate_bf = (ushort_t*)outc;                              // 33.5 MB
  ushort_t* hs_bf   = (ushort_t*)(outc + (size_t)ROWS * INTER * 2); // 33.5 MB
  ushort_t* Sbuf    = hs_bf;   // states overwrite hs_bf after GEMMs consume it

  // 0. conversions
  cvt_f32_bf16<<<(ROWS * DMODEL / 4 + 255) / 256, 256, 0, stream>>>(
      hs, hs_bf, ROWS * DMODEL);
  cvt_Wh<<<(WH_ROWS * DMODEL / 4 + 255) / 256, 256, 0, stream>>>(W_in, Wh_bf);
  cvt_f32_bf16<<<(DMODEL * DMODEL / 4 + 255) / 256, 256, 0, stream>>>(
      W_in, Wg_bf, DMODEL * DMODEL);
  cvt_f32_bf16<<<(DMODEL * DMODEL / 4 + 255) / 256, 256, 0, stream>>>(
      W_out, Wout_bf, DMODEL * DMODEL);

  // 1a. hBC_dt = hs @ Wh^T  (N padded to 2560, stores guarded to 2432)
  gemm256_nt<true, 10, HBCDT_PAD, HBCDT_PAD><<<dim3(10, 32), 512, 0, stream>>>(
      hs_bf, Wh_bf, hbcdt_bf);
  // 1b. gate = hs @ Wg^T
  gemm256_nt<true, 8, INTER, INTER><<<dim3(8, 32), 512, 0, stream>>>(
      hs_bf, Wg_bf, gate_bf);
  // 2. conv + silu (+ transposed B copy for scan-state MFMA)
  conv_silu_kernel<<<(ROWS * CONV_DIM + 255) / 256, 256, 0, stream>>>(
      hbcdt_bf, conv_w, conv_b, convo, BT_g);
  // 3. dt
  dtprep_kernel<<<(ROWS * NH + 255) / 256, 256, 0, stream>>>(
      hbcdt_bf, dt_bias, dt_s);
  // 4. chunked scan: MFMA local states -> combine -> SSD Y (MFMA)
  scan_state_kernel<<<B_ * NH * NC, 256, 0, stream>>>(
      convo, dt_s, A_log, BT_g, Sbuf, chunkA);
  state_combine_kernel<<<(B_ * NH * PDIM * (NSTATE / 4)) / 256, 256, 0, stream>>>(
      Sbuf, chunkA);
  ssd_y_kernel<<<B_ * NH * NC, 256, 0, stream>>>(
      convo, dt_s, A_log, D_param, Sbuf, ybuf_bf);
  // 5. gated rmsnorm (in-place on ybuf_bf)
  gated_rmsnorm_kernel<<<ROWS, 256, 0, stream>>>(ybuf_bf, gate_bf, norm_w);
  // 6. out = g @ W_out^T (fp32, overwrites d_out)
  gemm256_nt<false, 8, DMODEL, DMODEL><<<dim3(8, 32), 512, 0, stream>>>(
      ybuf_bf, Wout_bf, out);
}

// Round 5
// 632.779 us; speedup vs baseline: 1.0218x; 1.0218x over previous
//
#include <hip/hip_runtime.h>
#include <cstdint>
#include <cstddef>

// Problem constants
#define B_        2
#define LSEQ      4096
#define DMODEL    2048
#define NH        32
#define PDIM      64
#define NSTATE    128
#define KCONV     4
#define INTER     2048       // NH*PDIM
#define CONV_DIM  2304       // INTER + 2*NSTATE
#define HBCDT     2336       // CONV_DIM + NH
#define HBCDT_PAD 2432       // hbcdt row stride (19*128), unchanged
#define WH_ROWS   2560       // W_h padded rows for 256-wide GEMM tiles
#define ROWS      (B_*LSEQ)  // 8192
#define NC        32         // sequence chunks for the scan
#define CLEN      (LSEQ/NC)  // 128  (= Q)

typedef unsigned short ushort_t;
typedef short bf16x8 __attribute__((ext_vector_type(8)));
typedef float f32x4 __attribute__((ext_vector_type(4)));

__device__ __forceinline__ float siluf(float x) {
  return x / (1.0f + __expf(-x));
}
__device__ __forceinline__ float bf2f(ushort_t u) {
  union { unsigned int i; float f; } v; v.i = ((unsigned int)u) << 16; return v.f;
}
__device__ __forceinline__ ushort_t f2bf(float f) {
  union { float f; unsigned int i; } v; v.f = f;
  unsigned int r = v.i + 0x7fff + ((v.i >> 16) & 1);   // RNE
  return (ushort_t)(r >> 16);
}
__device__ __forceinline__ void async16(const void* g, void* l) {
  __builtin_amdgcn_global_load_lds(
      (const __attribute__((address_space(1))) unsigned int*)g,
      (__attribute__((address_space(3))) unsigned int*)l, 16, 0, 0);
}

// ---------------------------------------------------------------------------
// fp32 -> bf16 conversions
// ---------------------------------------------------------------------------
__global__ __launch_bounds__(256) void cvt_f32_bf16(
    const float* __restrict__ src, ushort_t* __restrict__ dst, int n) {
  const int i = (blockIdx.x * 256 + threadIdx.x) * 4;
  if (i >= n) return;
  float4 v = *(const float4*)(src + i);
  ushort4 o; o.x = f2bf(v.x); o.y = f2bf(v.y); o.z = f2bf(v.z); o.w = f2bf(v.w);
  *(ushort4*)(dst + i) = o;
}

// W_in rows [INTER, INTER+HBCDT) -> bf16 padded to WH_ROWS rows (zeros)
__global__ __launch_bounds__(256) void cvt_Wh(
    const float* __restrict__ W_in, ushort_t* __restrict__ dst) {
  const int i = (blockIdx.x * 256 + threadIdx.x) * 4;
  if (i >= WH_ROWS * DMODEL) return;
  const int r = i / DMODEL, c = i % DMODEL;
  ushort4 o;
  if (r < HBCDT) {
    float4 v = *(const float4*)(W_in + (size_t)(INTER + r) * DMODEL + c);
    o.x = f2bf(v.x); o.y = f2bf(v.y); o.z = f2bf(v.z); o.w = f2bf(v.w);
  } else {
    o.x = 0; o.y = 0; o.z = 0; o.w = 0;
  }
  *(ushort4*)(dst + i) = o;
}

// ---------------------------------------------------------------------------
// 256x256 8-phase bf16 NT GEMM, counted vmcnt (T4), minimal LDS reads.
// C[m,n] = sum_k A[m,k]*B[n,k], K = 2048 fixed, BK = 64, 8 waves (2M x 4N).
// Per K-tile per wave: 24 ds_read_b128 (16 A + 8 B, B-frags kept live across
// phases -- no re-reads), 64 MFMA in 4 phases of 16. NO forced lgkmcnt(0):
// plain-C++ ds_reads are dep-tracked, so the compiler emits fine-grained
// per-operand lgkmcnt waits, overlapping early MFMAs with the LDS drain
// (m97 asm evidence; forced drain was m141's -42%). Stage of tile j issued
// at tail of tile j-2 into the just-retired buffer; tail waits vmcnt(8)
// (only tile j-1's 8 loads), never vmcnt(0) in the main loop.
// T2 LDS granule swizzle, T5 setprio, T1 XCD bid swizzle (NWG % 8 == 0).
// ---------------------------------------------------------------------------
#define STAGE_A(CN, H, KTT) do {                                              \
    async16(Ast + (size_t)((H) * 128) * 2048 + (KTT) * 64,                    \
            smem_ + (CN) + (H) * 16384 + wave * 1024);                        \
    async16(Ast + (size_t)((H) * 128 + 64) * 2048 + (KTT) * 64,               \
            smem_ + (CN) + (H) * 16384 + 8192 + wave * 1024);                 \
  } while (0)

#define STAGE_B(CN, H, KTT) do {                                              \
    async16(Bst + (size_t)((H) * 128) * 2048 + (KTT) * 64,                    \
            smem_ + 65536 + (CN) + (H) * 16384 + wave * 1024);                \
    async16(Bst + (size_t)((H) * 128 + 64) * 2048 + (KTT) * 64,               \
            smem_ + 65536 + (CN) + (H) * 16384 + 8192 + wave * 1024);         \
  } while (0)

#define LDA(DST, CB, MH) do {                                                 \
    const char* ab_ = smem_ + (CB) + aro;                                     \
    _Pragma("unroll") for (int mi_ = 0; mi_ < 4; ++mi_) {                     \
      DST[mi_][0] = *(const bf16x8*)(ab_ + (MH) * 8192 + mi_ * 2048 + g0);    \
      DST[mi_][1] = *(const bf16x8*)(ab_ + (MH) * 8192 + mi_ * 2048 + g1);    \
    }                                                                         \
  } while (0)

#define LDB(DST, CB, NHH) do {                                                \
    const char* bb_ = smem_ + 65536 + (CB) + bro;                             \
    _Pragma("unroll") for (int ni_ = 0; ni_ < 2; ++ni_) {                     \
      DST[ni_][0] = *(const bf16x8*)(bb_ + (NHH) * 4096 + ni_ * 2048 + g0);   \
      DST[ni_][1] = *(const bf16x8*)(bb_ + (NHH) * 4096 + ni_ * 2048 + g1);   \
    }                                                                         \
  } while (0)

#define MFMAQ(MH, NHH, AF, BF)                                                \
  _Pragma("unroll") for (int mi_ = 0; mi_ < 4; ++mi_)                         \
  _Pragma("unroll") for (int ni_ = 0; ni_ < 2; ++ni_) {                       \
    f32x4& c_ = acc[(MH) * 4 + mi_][(NHH) * 2 + ni_];                         \
    c_ = __builtin_amdgcn_mfma_f32_16x16x32_bf16(AF[mi_][0], BF[ni_][0], c_, 0, 0, 0); \
    c_ = __builtin_amdgcn_mfma_f32_16x16x32_bf16(AF[mi_][1], BF[ni_][1], c_, 0, 0, 0); \
  }

// Phase: barriers delimit the MFMA cluster; NO forced lgkmcnt drain --
// register data-deps make the compiler emit minimal per-operand waits.
#define PH(X) do {                                                            \
    __builtin_amdgcn_s_barrier();                                             \
    __builtin_amdgcn_s_setprio(1);                                            \
    X;                                                                        \
    __builtin_amdgcn_s_setprio(0);                                            \
    __builtin_amdgcn_s_barrier();                                             \
  } while (0)

// Tail of a K-tile group: this wave's reads of buffer CN were all consumed
// by MFMAs of phases 1-4 (dep-ordered), so re-staging CN is safe. Counted
// vmcnt leaves the 8 just-issued loads in flight.
#define GROUP_TAIL_CNT(X, DOSTAGE, CN, KTT) do {                              \
    __builtin_amdgcn_s_barrier();                                             \
    __builtin_amdgcn_s_setprio(1);                                            \
    X;                                                                        \
    __builtin_amdgcn_s_setprio(0);                                            \
    if (DOSTAGE) {                                                            \
      STAGE_A(CN, 0, KTT); STAGE_A(CN, 1, KTT);                               \
      STAGE_B(CN, 0, KTT); STAGE_B(CN, 1, KTT);                               \
      asm volatile("s_waitcnt vmcnt(8)" ::: "memory");                        \
    } else {                                                                  \
      asm volatile("s_waitcnt vmcnt(0)" ::: "memory");                        \
    }                                                                         \
    __builtin_amdgcn_s_barrier();                                             \
  } while (0)

template <bool OUT_BF16, int NTN, int NVALID, int LDC>
__global__ __launch_bounds__(512, 2) void gemm256_nt(
    const ushort_t* __restrict__ A, const ushort_t* __restrict__ B,
    void* __restrict__ C) {
  __shared__ __align__(16) char smem_[131072];
  const int t    = threadIdx.x;
  const int lane = t & 63;
  const int wave = t >> 6;
  const int wm   = wave >> 2;   // 0..1  (M half of the tile)
  const int wn   = wave & 3;    // 0..3  (N quarter)

  // XCD-aware tile swizzle (NWG % 8 == 0 always here -> bijective)
  constexpr int NWG = NTN * 32;
  int bid = blockIdx.y * NTN + blockIdx.x;
  bid = (bid & 7) * (NWG >> 3) + (bid >> 3);
  const int m0 = (bid / NTN) * 256;
  const int n0 = (bid % NTN) * 256;

  // staging: thread covers row (wave*8 + lane>>3), granule (lane&7)^(lane>>3)
  const int srow = wave * 8 + (lane >> 3);
  const int scol = ((lane & 7) ^ (lane >> 3)) * 8;
  const ushort_t* Ast = A + (size_t)(m0 + srow) * 2048 + scol;
  const ushort_t* Bst = B + (size_t)(n0 + srow) * 2048 + scol;

  // fragment-read bases; row&7 == lane&7 for all fragment rows
  const int aro = (wm * 128 + (lane & 15)) * 128;
  const int bro = (wn * 64 + (lane & 15)) * 128;
  const int g0  = ((lane >> 4) ^ (lane & 7)) * 16;
  const int g1  = (((lane >> 4) + 4) ^ (lane & 7)) * 16;

  f32x4 acc[8][4];
#pragma unroll
  for (int i = 0; i < 8; ++i)
#pragma unroll
    for (int j = 0; j < 4; ++j) {
      f32x4 z = {0.f, 0.f, 0.f, 0.f};
      acc[i][j] = z;
    }
  bf16x8 af[4][2], bq0[2][2], bq1[2][2];

  // prologue: stage tile 0 -> buf0, tile 1 -> buf1; wait only for tile 0
  STAGE_A(0, 0, 0); STAGE_A(0, 1, 0);
  STAGE_B(0, 0, 0); STAGE_B(0, 1, 0);
  STAGE_A(32768, 0, 1); STAGE_A(32768, 1, 1);
  STAGE_B(32768, 0, 1); STAGE_B(32768, 1, 1);
  asm volatile("s_waitcnt vmcnt(8)" ::: "memory");
  __builtin_amdgcn_s_barrier();

  constexpr int NT = 2048 / 64;  // 32 K-tiles
  for (int kt = 0; kt < NT; kt += 2) {
    // ---- group A: compute tile kt from buf0; tail stages kt+2 -> buf0 ----
    LDA(af, 0, 0); LDB(bq0, 0, 0);
    PH(MFMAQ(0, 0, af, bq0));
    LDB(bq1, 0, 1);
    PH(MFMAQ(0, 1, af, bq1));
    LDA(af, 0, 1);                       // bq0/bq1 stay live -- no re-reads
    PH(MFMAQ(1, 0, af, bq0));
    GROUP_TAIL_CNT(MFMAQ(1, 1, af, bq1), (kt + 2) < NT, 0, kt + 2);
    // ---- group B: compute tile kt+1 from buf1; tail stages kt+3 -> buf1 ----
    LDA(af, 32768, 0); LDB(bq0, 32768, 0);
    PH(MFMAQ(0, 0, af, bq0));
    LDB(bq1, 32768, 1);
    PH(MFMAQ(0, 1, af, bq1));
    LDA(af, 32768, 1);
    PH(MFMAQ(1, 0, af, bq0));
    GROUP_TAIL_CNT(MFMAQ(1, 1, af, bq1), (kt + 3) < NT, 32768, kt + 3);
  }

  // epilogue: C/D mapping col=lane&15, row=(lane>>4)*4+reg
  const int mb = m0 + wm * 128 + (lane >> 4) * 4;
  const int nb = n0 + wn * 64 + (lane & 15);
#pragma unroll
  for (int mq = 0; mq < 8; ++mq)
#pragma unroll
    for (int nq = 0; nq < 4; ++nq)
#pragma unroll
      for (int r = 0; r < 4; ++r) {
        const int m = mb + mq * 16 + r;
        const int n = nb + nq * 16;
        if (n < NVALID) {
          if (OUT_BF16)
            ((ushort_t*)C)[(size_t)m * LDC + n] = f2bf(acc[mq][nq][r]);
          else
            ((float*)C)[(size_t)m * LDC + n] = acc[mq][nq][r];
        }
      }
}

// ---------------------------------------------------------------------------
// Depthwise causal conv1d (K=4) + bias + SiLU. Input hbcdt bf16 (ld 2432),
// output convo bf16 (ld 2304). Additionally writes the B section (c in
// [INTER, INTER+NSTATE)) transposed: BT_g[b][chunk][n][s_local] for the
// MFMA scan-state kernel (G=1: B is head-shared).
// ---------------------------------------------------------------------------
__global__ __launch_bounds__(256) void conv_silu_kernel(
    const ushort_t* __restrict__ hbcdt, const float* __restrict__ conv_w,
    const float* __restrict__ conv_b, ushort_t* __restrict__ convo,
    ushort_t* __restrict__ BT_g) {
  const int idx = blockIdx.x * 256 + threadIdx.x;
  if (idx >= ROWS * CONV_DIM) return;
  const int c   = idx % CONV_DIM;
  const int row = idx / CONV_DIM;
  const int l   = row & (LSEQ - 1);
  float acc = conv_b[c];
  const float* w = conv_w + c * KCONV;
#pragma unroll
  for (int k = 0; k < KCONV; ++k) {
    const int tt = l + k - (KCONV - 1);
    if (tt >= 0)
      acc = fmaf(bf2f(hbcdt[(size_t)(row + k - (KCONV - 1)) * HBCDT_PAD + c]), w[k], acc);
  }
  const ushort_t v = f2bf(siluf(acc));
  convo[idx] = v;
  if (c >= INTER && c < INTER + NSTATE) {
    const int n   = c - INTER;
    const int bb  = row >> 12;        // / LSEQ
    const int cch = l >> 7;           // / CLEN
    const int sl  = l & (CLEN - 1);
    BT_g[(((size_t)bb * NC + cch) * NSTATE + n) * CLEN + sl] = v;
  }
}

// ---------------------------------------------------------------------------
// dt = softplus(dt_raw + dt_bias)
// ---------------------------------------------------------------------------
__global__ __launch_bounds__(256) void dtprep_kernel(
    const ushort_t* __restrict__ hbcdt, const float* __restrict__ dt_bias,
    float* __restrict__ dt_s) {
  const int idx = blockIdx.x * 256 + threadIdx.x;
  if (idx >= ROWS * NH) return;
  const int h   = idx & (NH - 1);
  const int row = idx >> 5;
  float x = bf2f(hbcdt[(size_t)row * HBCDT_PAD + CONV_DIM + h]) + dt_bias[h];
  dt_s[idx] = (x > 20.f) ? x : log1pf(__expf(x));
}

// ---------------------------------------------------------------------------
// Chunked scan, pass 1 (MFMA form): per (b,h,c),
//   La = cumsum(-exp(A_log[h])*dt);  wgt[s] = dt_s * exp(La_end - La_s)
//   S_loc[p][n] = sum_s (x_s[p]*wgt[s]) * B_s[n]   -> NT MFMA, K=s=128
//   chunkA = exp(La_end)
// Grid: B*NH*NC = 2048 blocks x 256 thr (4 waves; wave w -> p rows w*16..+16).
// ---------------------------------------------------------------------------
#define XLD 272   // Xw^T row stride bytes (128*2 + 16 pad -> 2-way conflicts only)
__global__ __launch_bounds__(256) void scan_state_kernel(
    const ushort_t* __restrict__ convo, const float* __restrict__ dt_s,
    const float* __restrict__ A_log, const ushort_t* __restrict__ BT_g,
    ushort_t* __restrict__ Sbuf, float* __restrict__ chunkA) {
  __shared__ __align__(16) char XwT[64 * XLD];   // [p][s] bf16, weighted
  __shared__ float dt_sh[CLEN];
  __shared__ float wgt[CLEN];

  const int blk = blockIdx.x;
  const int c   = blk & (NC - 1);
  const int h   = (blk >> 5) & 31;
  const int b   = blk >> 10;
  const int t   = threadIdx.x;
  const int lane = t & 63;
  const int wave = t >> 6;
  const size_t crow = (size_t)(b * LSEQ + c * CLEN);

  if (t < CLEN) dt_sh[t] = dt_s[(crow + t) * NH + h];
  __syncthreads();

  if (wave == 0) {
    const float a = __expf(A_log[h]);
    float v0 = -a * dt_sh[lane];
    float v1 = -a * dt_sh[lane + 64];
#pragma unroll
    for (int off = 1; off < 64; off <<= 1) {
      float u0 = __shfl_up(v0, off);
      float u1 = __shfl_up(v1, off);
      if (lane >= off) { v0 += u0; v1 += u1; }
    }
    const float tot0 = __shfl(v0, 63);
    const float La0  = v0;
    const float La1  = v1 + tot0;
    const float Lend = __shfl(v1, 63) + tot0;
    wgt[lane]      = dt_sh[lane]      * __expf(Lend - La0);
    wgt[lane + 64] = dt_sh[lane + 64] * __expf(Lend - La1);
    if (lane == 0) chunkA[(b * NH + h) * NC + c] = __expf(Lend);
  }
  __syncthreads();

  // stage weighted Xw^T: thread lane = p, wave covers t in [wave*32, +32)
  {
    const int p = lane;
    const int xcol = h * PDIM + p;
#pragma unroll
    for (int oct = 0; oct < 4; ++oct) {
      const int t0 = wave * 32 + oct * 8;
      unsigned int pk[4];
#pragma unroll
      for (int e = 0; e < 4; ++e) {
        const float f0 = bf2f(convo[(crow + t0 + 2*e)     * CONV_DIM + xcol]) * wgt[t0 + 2*e];
        const float f1 = bf2f(convo[(crow + t0 + 2*e + 1) * CONV_DIM + xcol]) * wgt[t0 + 2*e + 1];
        pk[e] = (unsigned int)f2bf(f0) | ((unsigned int)f2bf(f1) << 16);
      }
      *(uint4*)(XwT + p * XLD + t0 * 2) = make_uint4(pk[0], pk[1], pk[2], pk[3]);
    }
  }
  __syncthreads();

  // MFMA: S_loc[p][n], A = Xw^T (LDS), B = BT_g (global, L2-hot)
  f32x4 acc[8];
#pragma unroll
  for (int j = 0; j < 8; ++j) {
    f32x4 z = {0.f, 0.f, 0.f, 0.f};
    acc[j] = z;
  }
  const int rowA = wave * 16 + (lane & 15);
  const int koff = (lane >> 4) * 8;
  const ushort_t* Bt = BT_g + ((size_t)b * NC + c) * NSTATE * CLEN;
#pragma unroll
  for (int k0 = 0; k0 < 4; ++k0) {
    bf16x8 af = *(const bf16x8*)(XwT + rowA * XLD + (k0 * 32 + koff) * 2);
#pragma unroll
    for (int j = 0; j < 8; ++j) {
      bf16x8 bfx = *(const bf16x8*)(Bt + (size_t)(j * 16 + (lane & 15)) * CLEN + k0 * 32 + koff);
      acc[j] = __builtin_amdgcn_mfma_f32_16x16x32_bf16(af, bfx, acc[j], 0, 0, 0);
    }
  }

  ushort_t* Sb = Sbuf + (((size_t)b * NC + c) * NH + h) * (PDIM * NSTATE);
  const int prow = wave * 16 + (lane >> 4) * 4;
  const int ncol = lane & 15;
#pragma unroll
  for (int j = 0; j < 8; ++j)
#pragma unroll
    for (int r = 0; r < 4; ++r)
      Sb[(size_t)(prow + r) * NSTATE + j * 16 + ncol] = f2bf(acc[j][r]);
}

// ---------------------------------------------------------------------------
// Chunked scan, pass 2: in-place serial combine over chunks.
// ---------------------------------------------------------------------------
__global__ __launch_bounds__(256) void state_combine_kernel(
    ushort_t* __restrict__ Sbuf, const float* __restrict__ chunkA) {
  const int idx = blockIdx.x * 256 + threadIdx.x;
  const int nq = idx & 31;
  const int p  = (idx >> 5) & 63;
  const int h  = (idx >> 11) & 31;
  const int b  = (idx >> 16) & 1;
  const float* ca = chunkA + (b * NH + h) * NC;

  float s0 = 0.f, s1 = 0.f, s2 = 0.f, s3 = 0.f;
#pragma unroll 4
  for (int c = 0; c < NC; ++c) {
    const size_t off = ((((size_t)b * NC + c) * NH + h) * PDIM + p) * NSTATE + nq * 4;
    ushort4 loc = *(const ushort4*)(Sbuf + off);
    ushort4 o;
    o.x = f2bf(s0); o.y = f2bf(s1); o.z = f2bf(s2); o.w = f2bf(s3);
    *(ushort4*)(Sbuf + off) = o;                 // Sin for chunk c
    const float a = ca[c];
    s0 = fmaf(a, s0, bf2f(loc.x));
    s1 = fmaf(a, s1, bf2f(loc.y));
    s2 = fmaf(a, s2, bf2f(loc.z));
    s3 = fmaf(a, s3, bf2f(loc.w));
  }
}

// ---------------------------------------------------------------------------
// SSD Y-kernel: per (b,h,c) chunk of Q=128,
//   La[t] = cumsum(-exp(A_log[h])*dt) over chunk
//   G = C @ B^T;  W[t,s] = (t>=s) ? G*dt[s]*exp(La[t]-La[s]) : 0  -> LDS bf16
//   Y = exp(La[t]) o (C @ Sin^T) + W @ X + D*x
// Grid: B*NH*NC = 2048 blocks x 256 thr (4 waves).
// ---------------------------------------------------------------------------
#define WLD 272   // W row stride bytes (128*2 + 16 pad -> 2-way bank conflicts only)
__global__ __launch_bounds__(256) void ssd_y_kernel(
    const ushort_t* __restrict__ convo, const float* __restrict__ dt_s,
    const float* __restrict__ A_log, const float* __restrict__ D_param,
    const ushort_t* __restrict__ Sbuf, ushort_t* __restrict__ ybuf) {
  __shared__ __align__(16) char XT[64 * 256];     // [p][t^sw] bf16
  __shared__ __align__(16) char Wsh[128 * WLD];   // [t][s] bf16, padded rows
  __shared__ float dt_sh[CLEN];
  __shared__ float La[CLEN];

  const int blk = blockIdx.x;
  const int c   = blk & (NC - 1);
  const int h   = (blk >> 5) & 31;
  const int b   = blk >> 10;
  const int t   = threadIdx.x;
  const int lane = t & 63;
  const int wave = t >> 6;

  const size_t crow = (size_t)(b * LSEQ + c * CLEN);

  // ---- stage X transposed into LDS (XOR swizzle on t within 64-t octets) ----
  {
    const int p = lane;
    const int xcol = h * PDIM + p;
#pragma unroll
    for (int oct = 0; oct < 4; ++oct) {
      const int tl0 = wave * 32 + oct * 8;
      unsigned int pk[4];
#pragma unroll
      for (int e = 0; e < 4; ++e) {
        ushort_t v0 = convo[(crow + tl0 + 2 * e) * CONV_DIM + xcol];
        ushort_t v1 = convo[(crow + tl0 + 2 * e + 1) * CONV_DIM + xcol];
        pk[e] = (unsigned int)v0 | ((unsigned int)v1 << 16);
      }
      const int tsw = tl0 ^ ((p & 7) << 3);
      *(uint4*)(XT + p * 256 + tsw * 2) = make_uint4(pk[0], pk[1], pk[2], pk[3]);
    }
  }
  // ---- stage dt for chunk ----
  if (t < CLEN) dt_sh[t] = dt_s[(crow + t) * NH + h];
  __syncthreads();

  // ---- wave 0: inclusive prefix sum of log(dA) = -a*dt ----
  if (wave == 0) {
    const float a = __expf(A_log[h]);
    float v0 = -a * dt_sh[lane];
    float v1 = -a * dt_sh[lane + 64];
#pragma unroll
    for (int off = 1; off < 64; off <<= 1) {
      float u0 = __shfl_up(v0, off);
      float u1 = __shfl_up(v1, off);
      if (lane >= off) { v0 += u0; v1 += u1; }
    }
    const float tot0 = __shfl(v0, 63);
    La[lane]      = v0;
    La[lane + 64] = v1 + tot0;
  }
  __syncthreads();

  // ---- phase 1: G = C @ B^T (per-wave 64x64 tile), then W -> LDS ----
  const int wt = wave & 1;
  const int ws = wave >> 1;
  const bool active = !(wt == 0 && ws == 1);   // strictly-upper tile is all zero

  f32x4 g[4][4];
#pragma unroll
  for (int i = 0; i < 4; ++i)
#pragma unroll
    for (int j = 0; j < 4; ++j) {
      f32x4 z = {0.f, 0.f, 0.f, 0.f};
      g[i][j] = z;
    }

  if (active) {
    for (int k0 = 0; k0 < 4; ++k0) {
      const int koct = k0 * 32 + (lane >> 4) * 8;
      bf16x8 cf[4], bfg[4];
#pragma unroll
      for (int i = 0; i < 4; ++i) {
        const int tg = wt * 64 + i * 16 + (lane & 15);
        cf[i] = *(const bf16x8*)(convo + (crow + tg) * CONV_DIM + INTER + NSTATE + koct);
        const int sg = ws * 64 + i * 16 + (lane & 15);
        bfg[i] = *(const bf16x8*)(convo + (crow + sg) * CONV_DIM + INTER + koct);
      }
#pragma unroll
      for (int i = 0; i < 4; ++i)
#pragma unroll
        for (int j = 0; j < 4; ++j)
          g[i][j] = __builtin_amdgcn_mfma_f32_16x16x32_bf16(cf[i], bfg[j], g[i][j], 0, 0, 0);
    }
  }
#pragma unroll
  for (int i = 0; i < 4; ++i) {
    const int tbase = wt * 64 + i * 16 + ((lane >> 4) << 2);
    float Lat[4];
#pragma unroll
    for (int r = 0; r < 4; ++r) Lat[r] = La[tbase + r];
#pragma unroll
    for (int j = 0; j < 4; ++j) {
      const int sl  = ws * 64 + j * 16 + (lane & 15);
      const float Las = La[sl];
      const float dts = dt_sh[sl];
#pragma unroll
      for (int r = 0; r < 4; ++r) {
        const int tl = tbase + r;
        float val = 0.f;
        if (active && tl >= sl)
          val = g[i][j][r] * dts * __expf(Lat[r] - Las);
        *(ushort_t*)(Wsh + tl * WLD + sl * 2) = f2bf(val);
      }
    }
  }
  __syncthreads();

  // ---- phase 2: Y = exp(La) o (C @ Sin^T) + W @ X ----
  const int yt = wave & 1;        // t-half
  const int yp = wave >> 1;       // p-half (32 p's per wave)
  f32x4 acc[4][2];
#pragma unroll
  for (int i = 0; i < 4; ++i)
#pragma unroll
    for (int j = 0; j < 2; ++j) {
      f32x4 z = {0.f, 0.f, 0.f, 0.f};
      acc[i][j] = z;
    }

  const ushort_t* Sb = Sbuf + (((size_t)b * NC + c) * NH + h) * PDIM * NSTATE;

  // Yinter: C @ Sin^T  (K = N = 128)
  for (int k0 = 0; k0 < 4; ++k0) {
    const int koct = k0 * 32 + (lane >> 4) * 8;
    bf16x8 af[4], sf[2];
#pragma unroll
    for (int i = 0; i < 4; ++i) {
      const int tg = yt * 64 + i * 16 + (lane & 15);
      af[i] = *(const bf16x8*)(convo + (crow + tg) * CONV_DIM + INTER + NSTATE + koct);
    }
#pragma unroll
    for (int j = 0; j < 2; ++j) {
      const int pr = yp * 32 + j * 16 + (lane & 15);
      sf[j] = *(const bf16x8*)(Sb + pr * NSTATE + koct);
    }
#pragma unroll
    for (int i = 0; i < 4; ++i)
#pragma unroll
      for (int j = 0; j < 2; ++j)
        acc[i][j] = __builtin_amdgcn_mfma_f32_16x16x32_bf16(af[i], sf[j], acc[i][j], 0, 0, 0);
  }
  // scale by exp(La[t]) in fp32
#pragma unroll
  for (int i = 0; i < 4; ++i) {
    const int tbase = yt * 64 + i * 16 + ((lane >> 4) << 2);
#pragma unroll
    for (int r = 0; r < 4; ++r) {
      const float e = __expf(La[tbase + r]);
#pragma unroll
      for (int j = 0; j < 2; ++j) acc[i][j][r] *= e;
    }
  }
  // Yintra: W @ X  (K = Q = 128; A from Wsh, B from XT)
  for (int k0 = 0; k0 < 4; ++k0) {
    const int koct = k0 * 32 + (lane >> 4) * 8;
    bf16x8 wf[4], xf[2];
#pragma unroll
    for (int i = 0; i < 4; ++i) {
      const int tl = yt * 64 + i * 16 + (lane & 15);
      wf[i] = *(const bf16x8*)(Wsh + tl * WLD + koct * 2);
    }
#pragma unroll
    for (int j = 0; j < 2; ++j) {
      const int pr  = yp * 32 + j * 16 + (lane & 15);
      const int tsw = koct ^ ((pr & 7) << 3);
      xf[j] = *(const bf16x8*)(XT + pr * 256 + tsw * 2);
    }
#pragma unroll
    for (int i = 0; i < 4; ++i)
#pragma unroll
      for (int j = 0; j < 2; ++j)
        acc[i][j] = __builtin_amdgcn_mfma_f32_16x16x32_bf16(wf[i], xf[j], acc[i][j], 0, 0, 0);
  }

  // ---- epilogue: + D*x, write y ----
  const float Dh = D_param[h];
#pragma unroll
  for (int i = 0; i < 4; ++i) {
    const int tbase = yt * 64 + i * 16 + ((lane >> 4) << 2);
#pragma unroll
    for (int j = 0; j < 2; ++j) {
      const int pr = yp * 32 + j * 16 + (lane & 15);
#pragma unroll
      for (int r = 0; r < 4; ++r) {
        const int tl  = tbase + r;
        const int tsw = tl ^ ((pr & 7) << 3);
        const float x = bf2f(*(const ushort_t*)(XT + pr * 256 + tsw * 2));
        ybuf[(crow + tl) * INTER + h * PDIM + pr] = f2bf(acc[i][j][r] + Dh * x);
      }
    }
  }
}

// ---------------------------------------------------------------------------
// Gated RMSNorm (bf16 in/out, in-place on y).
// ---------------------------------------------------------------------------
__global__ __launch_bounds__(256) void gated_rmsnorm_kernel(
    ushort_t* __restrict__ y, const ushort_t* __restrict__ gate,
    const float* __restrict__ norm_w) {
  const int row = blockIdx.x;
  ushort_t* yr = y + (size_t)row * INTER;
  const ushort_t* gr = gate + (size_t)row * INTER;
  const int t  = threadIdx.x;
  const int i0 = t * 8;

  ushort4 ya = *(const ushort4*)(yr + i0);
  ushort4 yb = *(const ushort4*)(yr + i0 + 4);
  ushort4 ga = *(const ushort4*)(gr + i0);
  ushort4 gb = *(const ushort4*)(gr + i0 + 4);

  float g[8];
  g[0] = bf2f(ya.x) * siluf(bf2f(ga.x));
  g[1] = bf2f(ya.y) * siluf(bf2f(ga.y));
  g[2] = bf2f(ya.z) * siluf(bf2f(ga.z));
  g[3] = bf2f(ya.w) * siluf(bf2f(ga.w));
  g[4] = bf2f(yb.x) * siluf(bf2f(gb.x));
  g[5] = bf2f(yb.y) * siluf(bf2f(gb.y));
  g[6] = bf2f(yb.z) * siluf(bf2f(gb.z));
  g[7] = bf2f(yb.w) * siluf(bf2f(gb.w));

  float ss = 0.f;
#pragma unroll
  for (int i = 0; i < 8; ++i) ss += g[i] * g[i];

  ss += __shfl_xor(ss, 32);
  ss += __shfl_xor(ss, 16);
  ss += __shfl_xor(ss, 8);
  ss += __shfl_xor(ss, 4);
  ss += __shfl_xor(ss, 2);
  ss += __shfl_xor(ss, 1);

  __shared__ float red[4];
  if ((t & 63) == 0) red[t >> 6] = ss;
  __syncthreads();
  const float tot = red[0] + red[1] + red[2] + red[3];
  const float scale = rsqrtf(tot * (1.0f / INTER) + 1e-5f);

  ushort4 o0, o1;
  o0.x = f2bf(g[0] * scale * norm_w[i0 + 0]);
  o0.y = f2bf(g[1] * scale * norm_w[i0 + 1]);
  o0.z = f2bf(g[2] * scale * norm_w[i0 + 2]);
  o0.w = f2bf(g[3] * scale * norm_w[i0 + 3]);
  o1.x = f2bf(g[4] * scale * norm_w[i0 + 4]);
  o1.y = f2bf(g[5] * scale * norm_w[i0 + 5]);
  o1.z = f2bf(g[6] * scale * norm_w[i0 + 6]);
  o1.w = f2bf(g[7] * scale * norm_w[i0 + 7]);
  *(ushort4*)(yr + i0)     = o0;
  *(ushort4*)(yr + i0 + 4) = o1;
}

// ---------------------------------------------------------------------------
// Workspace (~108 MB): hbcdt_bf(39.8, aliased by ybuf) | convo(37.7) |
// dt_s(1) | Wh_bf(10.5, 2560 rows) | Wg_bf(8.4) | Wout_bf(8.4) | chunkA(8KB) |
// BT_g(2). d_out scratch: [0,33.5MB) gate_bf; [33.5,67MB) hs_bf -> Sbuf.
// ---------------------------------------------------------------------------
extern "C" void kernel_launch(void* const* d_in, const int* in_sizes, int n_in,
                              void* d_out, int out_size, void* d_ws, size_t ws_size,
                              hipStream_t stream) {
  const float* hs      = (const float*)d_in[0];
  const float* W_in    = (const float*)d_in[1];
  const float* conv_w  = (const float*)d_in[2];
  const float* conv_b  = (const float*)d_in[3];
  const float* dt_bias = (const float*)d_in[4];
  const float* A_log   = (const float*)d_in[5];
  const float* D_param = (const float*)d_in[6];
  const float* norm_w  = (const float*)d_in[7];
  const float* W_out   = (const float*)d_in[8];
  float* out = (float*)d_out;

  char* ws = (char*)d_ws;
  size_t off = 0;
  ushort_t* hbcdt_bf = (ushort_t*)(ws + off); off += (size_t)ROWS * HBCDT_PAD * 2;
  ushort_t* convo    = (ushort_t*)(ws + off); off += (size_t)ROWS * CONV_DIM * 2;
  float*    dt_s     = (float*)(ws + off);    off += (size_t)ROWS * NH * 4;
  ushort_t* Wh_bf    = (ushort_t*)(ws + off); off += (size_t)WH_ROWS * DMODEL * 2;
  ushort_t* Wg_bf    = (ushort_t*)(ws + off); off += (size_t)DMODEL * DMODEL * 2;
  ushort_t* Wout_bf  = (ushort_t*)(ws + off); off += (size_t)DMODEL * DMODEL * 2;
  float*    chunkA   = (float*)(ws + off);    off += (size_t)B_ * NH * NC * 4;
  ushort_t* BT_g     = (ushort_t*)(ws + off); off += (size_t)B_ * NC * NSTATE * CLEN * 2;
  ushort_t* ybuf_bf  = hbcdt_bf;                       // alias (hBC_dt dead)

  char* outc = (char*)d_out;
  ushort_t* gate_bf = (ushort_t*)outc;                              // 33.5 MB
  ushort_t* hs_bf   = (ushort_t*)(outc + (size_t)ROWS * INTER * 2); // 33.5 MB
  ushort_t* Sbuf    = hs_bf;   // states overwrite hs_bf after GEMMs consume it

  // 0. conversions
  cvt_f32_bf16<<<(ROWS * DMODEL / 4 + 255) / 256, 256, 0, stream>>>(
      hs, hs_bf, ROWS * DMODEL);
  cvt_Wh<<<(WH_ROWS * DMODEL / 4 + 255) / 256, 256, 0, stream>>>(W_in, Wh_bf);
  cvt_f32_bf16<<<(DMODEL * DMODEL / 4 + 255) / 256, 256, 0, stream>>>(
      W_in, Wg_bf, DMODEL * DMODEL);
  cvt_f32_bf16<<<(DMODEL * DMODEL / 4 + 255) / 256, 256, 0, stream>>>(
      W_out, Wout_bf, DMODEL * DMODEL);

  // 1a. hBC_dt = hs @ Wh^T  (N padded to 2560, stores guarded to 2432)
  gemm256_nt<true, 10, HBCDT_PAD, HBCDT_PAD><<<dim3(10, 32), 512, 0, stream>>>(
      hs_bf, Wh_bf, hbcdt_bf);
  // 1b. gate = hs @ Wg^T
  gemm256_nt<true, 8, INTER, INTER><<<dim3(8, 32), 512, 0, stream>>>(
      hs_bf, Wg_bf, gate_bf);
  // 2. conv + silu (+ transposed B copy for scan-state MFMA)
  conv_silu_kernel<<<(ROWS * CONV_DIM + 255) / 256, 256, 0, stream>>>(
      hbcdt_bf, conv_w, conv_b, convo, BT_g);
  // 3. dt
  dtprep_kernel<<<(ROWS * NH + 255) / 256, 256, 0, stream>>>(
      hbcdt_bf, dt_bias, dt_s);
  // 4. chunked scan: MFMA local states -> combine -> SSD Y (MFMA)
  scan_state_kernel<<<B_ * NH * NC, 256, 0, stream>>>(
      convo, dt_s, A_log, BT_g, Sbuf, chunkA);
  state_combine_kernel<<<(B_ * NH * PDIM * (NSTATE / 4)) / 256, 256, 0, stream>>>(
      Sbuf, chunkA);
  ssd_y_kernel<<<B_ * NH * NC, 256, 0, stream>>>(
      convo, dt_s, A_log, D_param, Sbuf, ybuf_bf);
  // 5. gated rmsnorm (in-place on ybuf_bf)
  gated_rmsnorm_kernel<<<ROWS, 256, 0, stream>>>(ybuf_bf, gate_bf, norm_w);
  // 6. out = g @ W_out^T (fp32, overwrites d_out)
  gemm256_nt<false, 8, DMODEL, DMODEL><<<dim3(8, 32), 512, 0, stream>>>(
      ybuf_bf, Wout_bf, out);
}

// Round 6
// 594.579 us; speedup vs baseline: 1.0875x; 1.0642x over previous
//
#include <hip/hip_runtime.h>
#include <cstdint>
#include <cstddef>

// Problem constants
#define B_        2
#define LSEQ      4096
#define DMODEL    2048
#define NH        32
#define PDIM      64
#define NSTATE    128
#define KCONV     4
#define INTER     2048       // NH*PDIM
#define CONV_DIM  2304       // INTER + 2*NSTATE
#define HBCDT     2336       // CONV_DIM + NH
#define HBCDT_PAD 2432       // hbcdt row stride (19*128), unchanged
#define WH_ROWS   2560       // W_h padded rows (= 8 tiles of 320)
#define ROWS      (B_*LSEQ)  // 8192
#define NC        32         // sequence chunks for the scan
#define CLEN      (LSEQ/NC)  // 128  (= Q)

typedef unsigned short ushort_t;
typedef short bf16x8 __attribute__((ext_vector_type(8)));
typedef float f32x4 __attribute__((ext_vector_type(4)));

__device__ __forceinline__ float siluf(float x) {
  return x / (1.0f + __expf(-x));
}
__device__ __forceinline__ float bf2f(ushort_t u) {
  union { unsigned int i; float f; } v; v.i = ((unsigned int)u) << 16; return v.f;
}
__device__ __forceinline__ ushort_t f2bf(float f) {
  union { float f; unsigned int i; } v; v.f = f;
  unsigned int r = v.i + 0x7fff + ((v.i >> 16) & 1);   // RNE
  return (ushort_t)(r >> 16);
}
__device__ __forceinline__ void async16(const void* g, void* l) {
  __builtin_amdgcn_global_load_lds(
      (const __attribute__((address_space(1))) unsigned int*)g,
      (__attribute__((address_space(3))) unsigned int*)l, 16, 0, 0);
}

// ---------------------------------------------------------------------------
// fp32 -> bf16 conversions
// ---------------------------------------------------------------------------
__global__ __launch_bounds__(256) void cvt_f32_bf16(
    const float* __restrict__ src, ushort_t* __restrict__ dst, int n) {
  const int i = (blockIdx.x * 256 + threadIdx.x) * 4;
  if (i >= n) return;
  float4 v = *(const float4*)(src + i);
  ushort4 o; o.x = f2bf(v.x); o.y = f2bf(v.y); o.z = f2bf(v.z); o.w = f2bf(v.w);
  *(ushort4*)(dst + i) = o;
}

// W_in rows [INTER, INTER+HBCDT) -> bf16 padded to WH_ROWS rows (zeros)
__global__ __launch_bounds__(256) void cvt_Wh(
    const float* __restrict__ W_in, ushort_t* __restrict__ dst) {
  const int i = (blockIdx.x * 256 + threadIdx.x) * 4;
  if (i >= WH_ROWS * DMODEL) return;
  const int r = i / DMODEL, c = i % DMODEL;
  ushort4 o;
  if (r < HBCDT) {
    float4 v = *(const float4*)(W_in + (size_t)(INTER + r) * DMODEL + c);
    o.x = f2bf(v.x); o.y = f2bf(v.y); o.z = f2bf(v.z); o.w = f2bf(v.w);
  } else {
    o.x = 0; o.y = 0; o.z = 0; o.w = 0;
  }
  *(ushort4*)(dst + i) = o;
}

// ---------------------------------------------------------------------------
// Shared GEMM building blocks (bf16 NT, BK=64, 8 waves, counted vmcnt,
// T2 LDS granule swizzle via pre-swizzled global src, T5 setprio, T1 XCD
// bid swizzle). Two tile variants:
//   gemm256_nt: 256x256 tile (LDS 128 KiB), for N = 2048 launches (256 wg).
//   gemm320_nt: 256x320 tile (LDS 144 KiB), for N = 2560 (1a) -> exactly
//               256 wg = one full dispatch round, no tail (was 320 wg at
//               62.5% grid efficiency -- the measured 37% loss on 1a).
// ---------------------------------------------------------------------------
#define STAGE_A(CN, H, KTT) do {                                              \
    async16(Ast + (size_t)((H) * 128) * 2048 + (KTT) * 64,                    \
            smem_ + (CN) + (H) * 16384 + wave * 1024);                        \
    async16(Ast + (size_t)((H) * 128 + 64) * 2048 + (KTT) * 64,               \
            smem_ + (CN) + (H) * 16384 + 8192 + wave * 1024);                 \
  } while (0)

#define STAGE_B(CN, H, KTT) do {                                              \
    async16(Bst + (size_t)((H) * 128) * 2048 + (KTT) * 64,                    \
            smem_ + 65536 + (CN) + (H) * 16384 + wave * 1024);                \
    async16(Bst + (size_t)((H) * 128 + 64) * 2048 + (KTT) * 64,               \
            smem_ + 65536 + (CN) + (H) * 16384 + 8192 + wave * 1024);         \
  } while (0)

#define LDA(DST, CB, MH) do {                                                 \
    const char* ab_ = smem_ + (CB) + aro;                                     \
    _Pragma("unroll") for (int mi_ = 0; mi_ < 4; ++mi_) {                     \
      DST[mi_][0] = *(const bf16x8*)(ab_ + (MH) * 8192 + mi_ * 2048 + g0);    \
      DST[mi_][1] = *(const bf16x8*)(ab_ + (MH) * 8192 + mi_ * 2048 + g1);    \
    }                                                                         \
  } while (0)

#define LDB(DST, CB, NHH) do {                                                \
    const char* bb_ = smem_ + 65536 + (CB) + bro;                             \
    _Pragma("unroll") for (int ni_ = 0; ni_ < 2; ++ni_) {                     \
      DST[ni_][0] = *(const bf16x8*)(bb_ + (NHH) * 4096 + ni_ * 2048 + g0);   \
      DST[ni_][1] = *(const bf16x8*)(bb_ + (NHH) * 4096 + ni_ * 2048 + g1);   \
    }                                                                         \
  } while (0)

#define MFMAQ(MH, NHH, AF, BF)                                                \
  _Pragma("unroll") for (int mi_ = 0; mi_ < 4; ++mi_)                         \
  _Pragma("unroll") for (int ni_ = 0; ni_ < 2; ++ni_) {                       \
    f32x4& c_ = acc[(MH) * 4 + mi_][(NHH) * 2 + ni_];                         \
    c_ = __builtin_amdgcn_mfma_f32_16x16x32_bf16(AF[mi_][0], BF[ni_][0], c_, 0, 0, 0); \
    c_ = __builtin_amdgcn_mfma_f32_16x16x32_bf16(AF[mi_][1], BF[ni_][1], c_, 0, 0, 0); \
  }

// Phase: barriers delimit the MFMA cluster; no forced lgkmcnt drain --
// register data-deps make the compiler emit minimal per-operand waits.
#define PH(X) do {                                                            \
    __builtin_amdgcn_s_barrier();                                             \
    __builtin_amdgcn_s_setprio(1);                                            \
    X;                                                                        \
    __builtin_amdgcn_s_setprio(0);                                            \
    __builtin_amdgcn_s_barrier();                                             \
  } while (0)

#define GROUP_TAIL_CNT(X, DOSTAGE, CN, KTT) do {                              \
    __builtin_amdgcn_s_barrier();                                             \
    __builtin_amdgcn_s_setprio(1);                                            \
    X;                                                                        \
    __builtin_amdgcn_s_setprio(0);                                            \
    if (DOSTAGE) {                                                            \
      STAGE_A(CN, 0, KTT); STAGE_A(CN, 1, KTT);                               \
      STAGE_B(CN, 0, KTT); STAGE_B(CN, 1, KTT);                               \
      asm volatile("s_waitcnt vmcnt(8)" ::: "memory");                        \
    } else {                                                                  \
      asm volatile("s_waitcnt vmcnt(0)" ::: "memory");                        \
    }                                                                         \
    __builtin_amdgcn_s_barrier();                                             \
  } while (0)

template <bool OUT_BF16, int NTN, int NVALID, int LDC>
__global__ __launch_bounds__(512, 2) void gemm256_nt(
    const ushort_t* __restrict__ A, const ushort_t* __restrict__ B,
    void* __restrict__ C) {
  __shared__ __align__(16) char smem_[131072];
  const int t    = threadIdx.x;
  const int lane = t & 63;
  const int wave = t >> 6;
  const int wm   = wave >> 2;   // 0..1  (M half of the tile)
  const int wn   = wave & 3;    // 0..3  (N quarter)

  // XCD-aware tile swizzle (NWG % 8 == 0 always here -> bijective)
  constexpr int NWG = NTN * 32;
  int bid = blockIdx.y * NTN + blockIdx.x;
  bid = (bid & 7) * (NWG >> 3) + (bid >> 3);
  const int m0 = (bid / NTN) * 256;
  const int n0 = (bid % NTN) * 256;

  // staging: thread covers row (wave*8 + lane>>3), granule (lane&7)^(lane>>3)
  const int srow = wave * 8 + (lane >> 3);
  const int scol = ((lane & 7) ^ (lane >> 3)) * 8;
  const ushort_t* Ast = A + (size_t)(m0 + srow) * 2048 + scol;
  const ushort_t* Bst = B + (size_t)(n0 + srow) * 2048 + scol;

  // fragment-read bases; row&7 == lane&7 for all fragment rows
  const int aro = (wm * 128 + (lane & 15)) * 128;
  const int bro = (wn * 64 + (lane & 15)) * 128;
  const int g0  = ((lane >> 4) ^ (lane & 7)) * 16;
  const int g1  = (((lane >> 4) + 4) ^ (lane & 7)) * 16;

  f32x4 acc[8][4];
#pragma unroll
  for (int i = 0; i < 8; ++i)
#pragma unroll
    for (int j = 0; j < 4; ++j) {
      f32x4 z = {0.f, 0.f, 0.f, 0.f};
      acc[i][j] = z;
    }
  bf16x8 af[4][2], bq0[2][2], bq1[2][2];

  // prologue: stage tile 0 -> buf0, tile 1 -> buf1; wait only for tile 0
  STAGE_A(0, 0, 0); STAGE_A(0, 1, 0);
  STAGE_B(0, 0, 0); STAGE_B(0, 1, 0);
  STAGE_A(32768, 0, 1); STAGE_A(32768, 1, 1);
  STAGE_B(32768, 0, 1); STAGE_B(32768, 1, 1);
  asm volatile("s_waitcnt vmcnt(8)" ::: "memory");
  __builtin_amdgcn_s_barrier();

  constexpr int NT = 2048 / 64;  // 32 K-tiles
  for (int kt = 0; kt < NT; kt += 2) {
    // ---- group A: compute tile kt from buf0; tail stages kt+2 -> buf0 ----
    LDA(af, 0, 0); LDB(bq0, 0, 0);
    PH(MFMAQ(0, 0, af, bq0));
    LDB(bq1, 0, 1);
    PH(MFMAQ(0, 1, af, bq1));
    LDA(af, 0, 1);                       // bq0/bq1 stay live -- no re-reads
    PH(MFMAQ(1, 0, af, bq0));
    GROUP_TAIL_CNT(MFMAQ(1, 1, af, bq1), (kt + 2) < NT, 0, kt + 2);
    // ---- group B: compute tile kt+1 from buf1; tail stages kt+3 -> buf1 ----
    LDA(af, 32768, 0); LDB(bq0, 32768, 0);
    PH(MFMAQ(0, 0, af, bq0));
    LDB(bq1, 32768, 1);
    PH(MFMAQ(0, 1, af, bq1));
    LDA(af, 32768, 1);
    PH(MFMAQ(1, 0, af, bq0));
    GROUP_TAIL_CNT(MFMAQ(1, 1, af, bq1), (kt + 3) < NT, 32768, kt + 3);
  }

  // epilogue: C/D mapping col=lane&15, row=(lane>>4)*4+reg
  const int mb = m0 + wm * 128 + (lane >> 4) * 4;
  const int nb = n0 + wn * 64 + (lane & 15);
#pragma unroll
  for (int mq = 0; mq < 8; ++mq)
#pragma unroll
    for (int nq = 0; nq < 4; ++nq)
#pragma unroll
      for (int r = 0; r < 4; ++r) {
        const int m = mb + mq * 16 + r;
        const int n = nb + nq * 16;
        if (n < NVALID) {
          if (OUT_BF16)
            ((ushort_t*)C)[(size_t)m * LDC + n] = f2bf(acc[mq][nq][r]);
          else
            ((float*)C)[(size_t)m * LDC + n] = acc[mq][nq][r];
        }
      }
}

// ---------------------------------------------------------------------------
// 256x320-tile variant (1a only): N = 2560 = 8 tiles -> grid 32x8 = 256 wg,
// exactly one dispatch round (no tail). Per-wave output 128x80 (acc[8][5]).
// LDS 144 KiB: A[2][256][64] @ {0,32768}; B[2][320][64] @ 65536+{0,40960}.
// Staging 9 async16/wave/tile (A:4, B:5, 64-row units); tail vmcnt(9).
// Phases per K-tile: MFMA 24/16/24/16 (n-groups 3+2 per M-half).
// ---------------------------------------------------------------------------
#define ST_A64(CN, HB, KTT)                                                   \
    async16(Ast + (size_t)((HB) * 64) * 2048 + (KTT) * 64,                    \
            smem_ + (CN) + (HB) * 8192 + wave * 1024)
#define ST_B64(CN, HB, KTT)                                                   \
    async16(Bst + (size_t)((HB) * 64) * 2048 + (KTT) * 64,                    \
            smem_ + 65536 + (CN) + (HB) * 8192 + wave * 1024)
#define STAGE9(ACN, BCN, KTT) do {                                            \
    ST_A64(ACN, 0, KTT); ST_A64(ACN, 1, KTT);                                 \
    ST_A64(ACN, 2, KTT); ST_A64(ACN, 3, KTT);                                 \
    ST_B64(BCN, 0, KTT); ST_B64(BCN, 1, KTT); ST_B64(BCN, 2, KTT);            \
    ST_B64(BCN, 3, KTT); ST_B64(BCN, 4, KTT);                                 \
  } while (0)

#define LDB3(DST, BCN) do {                                                   \
    const char* bb_ = smem_ + 65536 + (BCN) + bro;                            \
    _Pragma("unroll") for (int ni_ = 0; ni_ < 3; ++ni_) {                     \
      DST[ni_][0] = *(const bf16x8*)(bb_ + ni_ * 2048 + g0);                  \
      DST[ni_][1] = *(const bf16x8*)(bb_ + ni_ * 2048 + g1);                  \
    }                                                                         \
  } while (0)

#define LDB2(DST, BCN) do {                                                   \
    const char* bb_ = smem_ + 65536 + (BCN) + bro;                            \
    _Pragma("unroll") for (int ni_ = 0; ni_ < 2; ++ni_) {                     \
      DST[ni_][0] = *(const bf16x8*)(bb_ + (3 + ni_) * 2048 + g0);            \
      DST[ni_][1] = *(const bf16x8*)(bb_ + (3 + ni_) * 2048 + g1);            \
    }                                                                         \
  } while (0)

#define MFMA_G(MH, NB, NCNT, AF, BF)                                          \
  _Pragma("unroll") for (int mi_ = 0; mi_ < 4; ++mi_)                         \
  _Pragma("unroll") for (int ni_ = 0; ni_ < NCNT; ++ni_) {                    \
    f32x4& c_ = acc[(MH) * 4 + mi_][(NB) + ni_];                              \
    c_ = __builtin_amdgcn_mfma_f32_16x16x32_bf16(AF[mi_][0], BF[ni_][0], c_, 0, 0, 0); \
    c_ = __builtin_amdgcn_mfma_f32_16x16x32_bf16(AF[mi_][1], BF[ni_][1], c_, 0, 0, 0); \
  }

#define GROUP_TAIL9(X, DOSTAGE, ACN, BCN, KTT) do {                           \
    __builtin_amdgcn_s_barrier();                                             \
    __builtin_amdgcn_s_setprio(1);                                            \
    X;                                                                        \
    __builtin_amdgcn_s_setprio(0);                                            \
    if (DOSTAGE) {                                                            \
      STAGE9(ACN, BCN, KTT);                                                  \
      asm volatile("s_waitcnt vmcnt(9)" ::: "memory");                        \
    } else {                                                                  \
      asm volatile("s_waitcnt vmcnt(0)" ::: "memory");                        \
    }                                                                         \
    __builtin_amdgcn_s_barrier();                                             \
  } while (0)

template <int NTN, int NVALID, int LDC>
__global__ __launch_bounds__(512, 2) void gemm320_nt(
    const ushort_t* __restrict__ A, const ushort_t* __restrict__ B,
    ushort_t* __restrict__ C) {
  __shared__ __align__(16) char smem_[147456];
  const int t    = threadIdx.x;
  const int lane = t & 63;
  const int wave = t >> 6;
  const int wm   = wave >> 2;   // 0..1
  const int wn   = wave & 3;    // 0..3

  constexpr int NWG = NTN * 32;
  int bid = blockIdx.y * NTN + blockIdx.x;
  bid = (bid & 7) * (NWG >> 3) + (bid >> 3);
  const int m0 = (bid / NTN) * 256;
  const int n0 = (bid % NTN) * 320;

  const int srow = wave * 8 + (lane >> 3);
  const int scol = ((lane & 7) ^ (lane >> 3)) * 8;
  const ushort_t* Ast = A + (size_t)(m0 + srow) * 2048 + scol;
  const ushort_t* Bst = B + (size_t)(n0 + srow) * 2048 + scol;

  // fragment-read bases; all fragment rows are == lane&7 (mod 8): wm*128,
  // wn*80, mi*16, ni*16 are all 0 mod 8 (80 & 7 == 0).
  const int aro = (wm * 128 + (lane & 15)) * 128;
  const int bro = (wn * 80 + (lane & 15)) * 128;
  const int g0  = ((lane >> 4) ^ (lane & 7)) * 16;
  const int g1  = (((lane >> 4) + 4) ^ (lane & 7)) * 16;

  f32x4 acc[8][5];
#pragma unroll
  for (int i = 0; i < 8; ++i)
#pragma unroll
    for (int j = 0; j < 5; ++j) {
      f32x4 z = {0.f, 0.f, 0.f, 0.f};
      acc[i][j] = z;
    }
  bf16x8 af[4][2], bqA[3][2], bqB[2][2];

  // prologue: tile 0 -> buf0, tile 1 -> buf1; wait only for tile 0's 9
  STAGE9(0, 0, 0);
  STAGE9(32768, 40960, 1);
  asm volatile("s_waitcnt vmcnt(9)" ::: "memory");
  __builtin_amdgcn_s_barrier();

  constexpr int NT = 2048 / 64;  // 32 K-tiles
  for (int kt = 0; kt < NT; kt += 2) {
    // ---- tile kt from buf0; tail stages kt+2 -> buf0 ----
    LDA(af, 0, 0); LDB3(bqA, 0);
    PH(MFMA_G(0, 0, 3, af, bqA));
    LDB2(bqB, 0);
    PH(MFMA_G(0, 3, 2, af, bqB));
    LDA(af, 0, 1);                     // bqA/bqB stay live for M-half 1
    PH(MFMA_G(1, 0, 3, af, bqA));
    GROUP_TAIL9(MFMA_G(1, 3, 2, af, bqB), (kt + 2) < NT, 0, 0, kt + 2);
    // ---- tile kt+1 from buf1; tail stages kt+3 -> buf1 ----
    LDA(af, 32768, 0); LDB3(bqA, 40960);
    PH(MFMA_G(0, 0, 3, af, bqA));
    LDB2(bqB, 40960);
    PH(MFMA_G(0, 3, 2, af, bqB));
    LDA(af, 32768, 1);
    PH(MFMA_G(1, 0, 3, af, bqA));
    GROUP_TAIL9(MFMA_G(1, 3, 2, af, bqB), (kt + 3) < NT, 32768, 40960, kt + 3);
  }

  // epilogue
  const int mb = m0 + wm * 128 + (lane >> 4) * 4;
  const int nb = n0 + wn * 80 + (lane & 15);
#pragma unroll
  for (int mq = 0; mq < 8; ++mq)
#pragma unroll
    for (int nq = 0; nq < 5; ++nq)
#pragma unroll
      for (int r = 0; r < 4; ++r) {
        const int m = mb + mq * 16 + r;
        const int n = nb + nq * 16;
        if (n < NVALID)
          C[(size_t)m * LDC + n] = f2bf(acc[mq][nq][r]);
      }
}

// ---------------------------------------------------------------------------
// Depthwise causal conv1d (K=4) + bias + SiLU. Input hbcdt bf16 (ld 2432),
// output convo bf16 (ld 2304). Additionally writes the B section (c in
// [INTER, INTER+NSTATE)) transposed: BT_g[b][chunk][n][s_local] for the
// MFMA scan-state kernel (G=1: B is head-shared).
// ---------------------------------------------------------------------------
__global__ __launch_bounds__(256) void conv_silu_kernel(
    const ushort_t* __restrict__ hbcdt, const float* __restrict__ conv_w,
    const float* __restrict__ conv_b, ushort_t* __restrict__ convo,
    ushort_t* __restrict__ BT_g) {
  const int idx = blockIdx.x * 256 + threadIdx.x;
  if (idx >= ROWS * CONV_DIM) return;
  const int c   = idx % CONV_DIM;
  const int row = idx / CONV_DIM;
  const int l   = row & (LSEQ - 1);
  float acc = conv_b[c];
  const float* w = conv_w + c * KCONV;
#pragma unroll
  for (int k = 0; k < KCONV; ++k) {
    const int tt = l + k - (KCONV - 1);
    if (tt >= 0)
      acc = fmaf(bf2f(hbcdt[(size_t)(row + k - (KCONV - 1)) * HBCDT_PAD + c]), w[k], acc);
  }
  const ushort_t v = f2bf(siluf(acc));
  convo[idx] = v;
  if (c >= INTER && c < INTER + NSTATE) {
    const int n   = c - INTER;
    const int bb  = row >> 12;        // / LSEQ
    const int cch = l >> 7;           // / CLEN
    const int sl  = l & (CLEN - 1);
    BT_g[(((size_t)bb * NC + cch) * NSTATE + n) * CLEN + sl] = v;
  }
}

// ---------------------------------------------------------------------------
// dt = softplus(dt_raw + dt_bias)
// ---------------------------------------------------------------------------
__global__ __launch_bounds__(256) void dtprep_kernel(
    const ushort_t* __restrict__ hbcdt, const float* __restrict__ dt_bias,
    float* __restrict__ dt_s) {
  const int idx = blockIdx.x * 256 + threadIdx.x;
  if (idx >= ROWS * NH) return;
  const int h   = idx & (NH - 1);
  const int row = idx >> 5;
  float x = bf2f(hbcdt[(size_t)row * HBCDT_PAD + CONV_DIM + h]) + dt_bias[h];
  dt_s[idx] = (x > 20.f) ? x : log1pf(__expf(x));
}

// ---------------------------------------------------------------------------
// Chunked scan, pass 1 (MFMA form): per (b,h,c),
//   La = cumsum(-exp(A_log[h])*dt);  wgt[s] = dt_s * exp(La_end - La_s)
//   S_loc[p][n] = sum_s (x_s[p]*wgt[s]) * B_s[n]   -> NT MFMA, K=s=128
//   chunkA = exp(La_end)
// Grid: B*NH*NC = 2048 blocks x 256 thr (4 waves; wave w -> p rows w*16..+16).
// ---------------------------------------------------------------------------
#define XLD 272   // Xw^T row stride bytes (128*2 + 16 pad -> 2-way conflicts only)
__global__ __launch_bounds__(256) void scan_state_kernel(
    const ushort_t* __restrict__ convo, const float* __restrict__ dt_s,
    const float* __restrict__ A_log, const ushort_t* __restrict__ BT_g,
    ushort_t* __restrict__ Sbuf, float* __restrict__ chunkA) {
  __shared__ __align__(16) char XwT[64 * XLD];   // [p][s] bf16, weighted
  __shared__ float dt_sh[CLEN];
  __shared__ float wgt[CLEN];

  const int blk = blockIdx.x;
  const int c   = blk & (NC - 1);
  const int h   = (blk >> 5) & 31;
  const int b   = blk >> 10;
  const int t   = threadIdx.x;
  const int lane = t & 63;
  const int wave = t >> 6;
  const size_t crow = (size_t)(b * LSEQ + c * CLEN);

  if (t < CLEN) dt_sh[t] = dt_s[(crow + t) * NH + h];
  __syncthreads();

  if (wave == 0) {
    const float a = __expf(A_log[h]);
    float v0 = -a * dt_sh[lane];
    float v1 = -a * dt_sh[lane + 64];
#pragma unroll
    for (int off = 1; off < 64; off <<= 1) {
      float u0 = __shfl_up(v0, off);
      float u1 = __shfl_up(v1, off);
      if (lane >= off) { v0 += u0; v1 += u1; }
    }
    const float tot0 = __shfl(v0, 63);
    const float La0  = v0;
    const float La1  = v1 + tot0;
    const float Lend = __shfl(v1, 63) + tot0;
    wgt[lane]      = dt_sh[lane]      * __expf(Lend - La0);
    wgt[lane + 64] = dt_sh[lane + 64] * __expf(Lend - La1);
    if (lane == 0) chunkA[(b * NH + h) * NC + c] = __expf(Lend);
  }
  __syncthreads();

  // stage weighted Xw^T: thread lane = p, wave covers t in [wave*32, +32)
  {
    const int p = lane;
    const int xcol = h * PDIM + p;
#pragma unroll
    for (int oct = 0; oct < 4; ++oct) {
      const int t0 = wave * 32 + oct * 8;
      unsigned int pk[4];
#pragma unroll
      for (int e = 0; e < 4; ++e) {
        const float f0 = bf2f(convo[(crow + t0 + 2*e)     * CONV_DIM + xcol]) * wgt[t0 + 2*e];
        const float f1 = bf2f(convo[(crow + t0 + 2*e + 1) * CONV_DIM + xcol]) * wgt[t0 + 2*e + 1];
        pk[e] = (unsigned int)f2bf(f0) | ((unsigned int)f2bf(f1) << 16);
      }
      *(uint4*)(XwT + p * XLD + t0 * 2) = make_uint4(pk[0], pk[1], pk[2], pk[3]);
    }
  }
  __syncthreads();

  // MFMA: S_loc[p][n], A = Xw^T (LDS), B = BT_g (global, L2-hot)
  f32x4 acc[8];
#pragma unroll
  for (int j = 0; j < 8; ++j) {
    f32x4 z = {0.f, 0.f, 0.f, 0.f};
    acc[j] = z;
  }
  const int rowA = wave * 16 + (lane & 15);
  const int koff = (lane >> 4) * 8;
  const ushort_t* Bt = BT_g + ((size_t)b * NC + c) * NSTATE * CLEN;
#pragma unroll
  for (int k0 = 0; k0 < 4; ++k0) {
    bf16x8 af = *(const bf16x8*)(XwT + rowA * XLD + (k0 * 32 + koff) * 2);
#pragma unroll
    for (int j = 0; j < 8; ++j) {
      bf16x8 bfx = *(const bf16x8*)(Bt + (size_t)(j * 16 + (lane & 15)) * CLEN + k0 * 32 + koff);
      acc[j] = __builtin_amdgcn_mfma_f32_16x16x32_bf16(af, bfx, acc[j], 0, 0, 0);
    }
  }

  ushort_t* Sb = Sbuf + (((size_t)b * NC + c) * NH + h) * (PDIM * NSTATE);
  const int prow = wave * 16 + (lane >> 4) * 4;
  const int ncol = lane & 15;
#pragma unroll
  for (int j = 0; j < 8; ++j)
#pragma unroll
    for (int r = 0; r < 4; ++r)
      Sb[(size_t)(prow + r) * NSTATE + j * 16 + ncol] = f2bf(acc[j][r]);
}

// ---------------------------------------------------------------------------
// Chunked scan, pass 2: in-place serial combine over chunks.
// ---------------------------------------------------------------------------
__global__ __launch_bounds__(256) void state_combine_kernel(
    ushort_t* __restrict__ Sbuf, const float* __restrict__ chunkA) {
  const int idx = blockIdx.x * 256 + threadIdx.x;
  const int nq = idx & 31;
  const int p  = (idx >> 5) & 63;
  const int h  = (idx >> 11) & 31;
  const int b  = (idx >> 16) & 1;
  const float* ca = chunkA + (b * NH + h) * NC;

  float s0 = 0.f, s1 = 0.f, s2 = 0.f, s3 = 0.f;
#pragma unroll 4
  for (int c = 0; c < NC; ++c) {
    const size_t off = ((((size_t)b * NC + c) * NH + h) * PDIM + p) * NSTATE + nq * 4;
    ushort4 loc = *(const ushort4*)(Sbuf + off);
    ushort4 o;
    o.x = f2bf(s0); o.y = f2bf(s1); o.z = f2bf(s2); o.w = f2bf(s3);
    *(ushort4*)(Sbuf + off) = o;                 // Sin for chunk c
    const float a = ca[c];
    s0 = fmaf(a, s0, bf2f(loc.x));
    s1 = fmaf(a, s1, bf2f(loc.y));
    s2 = fmaf(a, s2, bf2f(loc.z));
    s3 = fmaf(a, s3, bf2f(loc.w));
  }
}

// ---------------------------------------------------------------------------
// SSD Y-kernel: per (b,h,c) chunk of Q=128,
//   La[t] = cumsum(-exp(A_log[h])*dt) over chunk
//   G = C @ B^T;  W[t,s] = (t>=s) ? G*dt[s]*exp(La[t]-La[s]) : 0  -> LDS bf16
//   Y = exp(La[t]) o (C @ Sin^T) + W @ X + D*x
// Grid: B*NH*NC = 2048 blocks x 256 thr (4 waves).
// ---------------------------------------------------------------------------
#define WLD 272   // W row stride bytes (128*2 + 16 pad -> 2-way bank conflicts only)
__global__ __launch_bounds__(256) void ssd_y_kernel(
    const ushort_t* __restrict__ convo, const float* __restrict__ dt_s,
    const float* __restrict__ A_log, const float* __restrict__ D_param,
    const ushort_t* __restrict__ Sbuf, ushort_t* __restrict__ ybuf) {
  __shared__ __align__(16) char XT[64 * 256];     // [p][t^sw] bf16
  __shared__ __align__(16) char Wsh[128 * WLD];   // [t][s] bf16, padded rows
  __shared__ float dt_sh[CLEN];
  __shared__ float La[CLEN];

  const int blk = blockIdx.x;
  const int c   = blk & (NC - 1);
  const int h   = (blk >> 5) & 31;
  const int b   = blk >> 10;
  const int t   = threadIdx.x;
  const int lane = t & 63;
  const int wave = t >> 6;

  const size_t crow = (size_t)(b * LSEQ + c * CLEN);

  // ---- stage X transposed into LDS (XOR swizzle on t within 64-t octets) ----
  {
    const int p = lane;
    const int xcol = h * PDIM + p;
#pragma unroll
    for (int oct = 0; oct < 4; ++oct) {
      const int tl0 = wave * 32 + oct * 8;
      unsigned int pk[4];
#pragma unroll
      for (int e = 0; e < 4; ++e) {
        ushort_t v0 = convo[(crow + tl0 + 2 * e) * CONV_DIM + xcol];
        ushort_t v1 = convo[(crow + tl0 + 2 * e + 1) * CONV_DIM + xcol];
        pk[e] = (unsigned int)v0 | ((unsigned int)v1 << 16);
      }
      const int tsw = tl0 ^ ((p & 7) << 3);
      *(uint4*)(XT + p * 256 + tsw * 2) = make_uint4(pk[0], pk[1], pk[2], pk[3]);
    }
  }
  // ---- stage dt for chunk ----
  if (t < CLEN) dt_sh[t] = dt_s[(crow + t) * NH + h];
  __syncthreads();

  // ---- wave 0: inclusive prefix sum of log(dA) = -a*dt ----
  if (wave == 0) {
    const float a = __expf(A_log[h]);
    float v0 = -a * dt_sh[lane];
    float v1 = -a * dt_sh[lane + 64];
#pragma unroll
    for (int off = 1; off < 64; off <<= 1) {
      float u0 = __shfl_up(v0, off);
      float u1 = __shfl_up(v1, off);
      if (lane >= off) { v0 += u0; v1 += u1; }
    }
    const float tot0 = __shfl(v0, 63);
    La[lane]      = v0;
    La[lane + 64] = v1 + tot0;
  }
  __syncthreads();

  // ---- phase 1: G = C @ B^T (per-wave 64x64 tile), then W -> LDS ----
  const int wt = wave & 1;
  const int ws = wave >> 1;
  const bool active = !(wt == 0 && ws == 1);   // strictly-upper tile is all zero

  f32x4 g[4][4];
#pragma unroll
  for (int i = 0; i < 4; ++i)
#pragma unroll
    for (int j = 0; j < 4; ++j) {
      f32x4 z = {0.f, 0.f, 0.f, 0.f};
      g[i][j] = z;
    }

  if (active) {
    for (int k0 = 0; k0 < 4; ++k0) {
      const int koct = k0 * 32 + (lane >> 4) * 8;
      bf16x8 cf[4], bfg[4];
#pragma unroll
      for (int i = 0; i < 4; ++i) {
        const int tg = wt * 64 + i * 16 + (lane & 15);
        cf[i] = *(const bf16x8*)(convo + (crow + tg) * CONV_DIM + INTER + NSTATE + koct);
        const int sg = ws * 64 + i * 16 + (lane & 15);
        bfg[i] = *(const bf16x8*)(convo + (crow + sg) * CONV_DIM + INTER + koct);
      }
#pragma unroll
      for (int i = 0; i < 4; ++i)
#pragma unroll
        for (int j = 0; j < 4; ++j)
          g[i][j] = __builtin_amdgcn_mfma_f32_16x16x32_bf16(cf[i], bfg[j], g[i][j], 0, 0, 0);
    }
  }
#pragma unroll
  for (int i = 0; i < 4; ++i) {
    const int tbase = wt * 64 + i * 16 + ((lane >> 4) << 2);
    float Lat[4];
#pragma unroll
    for (int r = 0; r < 4; ++r) Lat[r] = La[tbase + r];
#pragma unroll
    for (int j = 0; j < 4; ++j) {
      const int sl  = ws * 64 + j * 16 + (lane & 15);
      const float Las = La[sl];
      const float dts = dt_sh[sl];
#pragma unroll
      for (int r = 0; r < 4; ++r) {
        const int tl = tbase + r;
        float val = 0.f;
        if (active && tl >= sl)
          val = g[i][j][r] * dts * __expf(Lat[r] - Las);
        *(ushort_t*)(Wsh + tl * WLD + sl * 2) = f2bf(val);
      }
    }
  }
  __syncthreads();

  // ---- phase 2: Y = exp(La) o (C @ Sin^T) + W @ X ----
  const int yt = wave & 1;        // t-half
  const int yp = wave >> 1;       // p-half (32 p's per wave)
  f32x4 acc[4][2];
#pragma unroll
  for (int i = 0; i < 4; ++i)
#pragma unroll
    for (int j = 0; j < 2; ++j) {
      f32x4 z = {0.f, 0.f, 0.f, 0.f};
      acc[i][j] = z;
    }

  const ushort_t* Sb = Sbuf + (((size_t)b * NC + c) * NH + h) * PDIM * NSTATE;

  // Yinter: C @ Sin^T  (K = N = 128)
  for (int k0 = 0; k0 < 4; ++k0) {
    const int koct = k0 * 32 + (lane >> 4) * 8;
    bf16x8 af[4], sf[2];
#pragma unroll
    for (int i = 0; i < 4; ++i) {
      const int tg = yt * 64 + i * 16 + (lane & 15);
      af[i] = *(const bf16x8*)(convo + (crow + tg) * CONV_DIM + INTER + NSTATE + koct);
    }
#pragma unroll
    for (int j = 0; j < 2; ++j) {
      const int pr = yp * 32 + j * 16 + (lane & 15);
      sf[j] = *(const bf16x8*)(Sb + pr * NSTATE + koct);
    }
#pragma unroll
    for (int i = 0; i < 4; ++i)
#pragma unroll
      for (int j = 0; j < 2; ++j)
        acc[i][j] = __builtin_amdgcn_mfma_f32_16x16x32_bf16(af[i], sf[j], acc[i][j], 0, 0, 0);
  }
  // scale by exp(La[t]) in fp32
#pragma unroll
  for (int i = 0; i < 4; ++i) {
    const int tbase = yt * 64 + i * 16 + ((lane >> 4) << 2);
#pragma unroll
    for (int r = 0; r < 4; ++r) {
      const float e = __expf(La[tbase + r]);
#pragma unroll
      for (int j = 0; j < 2; ++j) acc[i][j][r] *= e;
    }
  }
  // Yintra: W @ X  (K = Q = 128; A from Wsh, B from XT)
  for (int k0 = 0; k0 < 4; ++k0) {
    const int koct = k0 * 32 + (lane >> 4) * 8;
    bf16x8 wf[4], xf[2];
#pragma unroll
    for (int i = 0; i < 4; ++i) {
      const int tl = yt * 64 + i * 16 + (lane & 15);
      wf[i] = *(const bf16x8*)(Wsh + tl * WLD + koct * 2);
    }
#pragma unroll
    for (int j = 0; j < 2; ++j) {
      const int pr  = yp * 32 + j * 16 + (lane & 15);
      const int tsw = koct ^ ((pr & 7) << 3);
      xf[j] = *(const bf16x8*)(XT + pr * 256 + tsw * 2);
    }
#pragma unroll
    for (int i = 0; i < 4; ++i)
#pragma unroll
      for (int j = 0; j < 2; ++j)
        acc[i][j] = __builtin_amdgcn_mfma_f32_16x16x32_bf16(wf[i], xf[j], acc[i][j], 0, 0, 0);
  }

  // ---- epilogue: + D*x, write y ----
  const float Dh = D_param[h];
#pragma unroll
  for (int i = 0; i < 4; ++i) {
    const int tbase = yt * 64 + i * 16 + ((lane >> 4) << 2);
#pragma unroll
    for (int j = 0; j < 2; ++j) {
      const int pr = yp * 32 + j * 16 + (lane & 15);
#pragma unroll
      for (int r = 0; r < 4; ++r) {
        const int tl  = tbase + r;
        const int tsw = tl ^ ((pr & 7) << 3);
        const float x = bf2f(*(const ushort_t*)(XT + pr * 256 + tsw * 2));
        ybuf[(crow + tl) * INTER + h * PDIM + pr] = f2bf(acc[i][j][r] + Dh * x);
      }
    }
  }
}

// ---------------------------------------------------------------------------
// Gated RMSNorm (bf16 in/out, in-place on y).
// ---------------------------------------------------------------------------
__global__ __launch_bounds__(256) void gated_rmsnorm_kernel(
    ushort_t* __restrict__ y, const ushort_t* __restrict__ gate,
    const float* __restrict__ norm_w) {
  const int row = blockIdx.x;
  ushort_t* yr = y + (size_t)row * INTER;
  const ushort_t* gr = gate + (size_t)row * INTER;
  const int t  = threadIdx.x;
  const int i0 = t * 8;

  ushort4 ya = *(const ushort4*)(yr + i0);
  ushort4 yb = *(const ushort4*)(yr + i0 + 4);
  ushort4 ga = *(const ushort4*)(gr + i0);
  ushort4 gb = *(const ushort4*)(gr + i0 + 4);

  float g[8];
  g[0] = bf2f(ya.x) * siluf(bf2f(ga.x));
  g[1] = bf2f(ya.y) * siluf(bf2f(ga.y));
  g[2] = bf2f(ya.z) * siluf(bf2f(ga.z));
  g[3] = bf2f(ya.w) * siluf(bf2f(ga.w));
  g[4] = bf2f(yb.x) * siluf(bf2f(gb.x));
  g[5] = bf2f(yb.y) * siluf(bf2f(gb.y));
  g[6] = bf2f(yb.z) * siluf(bf2f(gb.z));
  g[7] = bf2f(yb.w) * siluf(bf2f(gb.w));

  float ss = 0.f;
#pragma unroll
  for (int i = 0; i < 8; ++i) ss += g[i] * g[i];

  ss += __shfl_xor(ss, 32);
  ss += __shfl_xor(ss, 16);
  ss += __shfl_xor(ss, 8);
  ss += __shfl_xor(ss, 4);
  ss += __shfl_xor(ss, 2);
  ss += __shfl_xor(ss, 1);

  __shared__ float red[4];
  if ((t & 63) == 0) red[t >> 6] = ss;
  __syncthreads();
  const float tot = red[0] + red[1] + red[2] + red[3];
  const float scale = rsqrtf(tot * (1.0f / INTER) + 1e-5f);

  ushort4 o0, o1;
  o0.x = f2bf(g[0] * scale * norm_w[i0 + 0]);
  o0.y = f2bf(g[1] * scale * norm_w[i0 + 1]);
  o0.z = f2bf(g[2] * scale * norm_w[i0 + 2]);
  o0.w = f2bf(g[3] * scale * norm_w[i0 + 3]);
  o1.x = f2bf(g[4] * scale * norm_w[i0 + 4]);
  o1.y = f2bf(g[5] * scale * norm_w[i0 + 5]);
  o1.z = f2bf(g[6] * scale * norm_w[i0 + 6]);
  o1.w = f2bf(g[7] * scale * norm_w[i0 + 7]);
  *(ushort4*)(yr + i0)     = o0;
  *(ushort4*)(yr + i0 + 4) = o1;
}

// ---------------------------------------------------------------------------
// Workspace (~108 MB): hbcdt_bf(39.8, aliased by ybuf) | convo(37.7) |
// dt_s(1) | Wh_bf(10.5, 2560 rows) | Wg_bf(8.4) | Wout_bf(8.4) | chunkA(8KB) |
// BT_g(2). d_out scratch: [0,33.5MB) gate_bf; [33.5,67MB) hs_bf -> Sbuf.
// ---------------------------------------------------------------------------
extern "C" void kernel_launch(void* const* d_in, const int* in_sizes, int n_in,
                              void* d_out, int out_size, void* d_ws, size_t ws_size,
                              hipStream_t stream) {
  const float* hs      = (const float*)d_in[0];
  const float* W_in    = (const float*)d_in[1];
  const float* conv_w  = (const float*)d_in[2];
  const float* conv_b  = (const float*)d_in[3];
  const float* dt_bias = (const float*)d_in[4];
  const float* A_log   = (const float*)d_in[5];
  const float* D_param = (const float*)d_in[6];
  const float* norm_w  = (const float*)d_in[7];
  const float* W_out   = (const float*)d_in[8];
  float* out = (float*)d_out;

  char* ws = (char*)d_ws;
  size_t off = 0;
  ushort_t* hbcdt_bf = (ushort_t*)(ws + off); off += (size_t)ROWS * HBCDT_PAD * 2;
  ushort_t* convo    = (ushort_t*)(ws + off); off += (size_t)ROWS * CONV_DIM * 2;
  float*    dt_s     = (float*)(ws + off);    off += (size_t)ROWS * NH * 4;
  ushort_t* Wh_bf    = (ushort_t*)(ws + off); off += (size_t)WH_ROWS * DMODEL * 2;
  ushort_t* Wg_bf    = (ushort_t*)(ws + off); off += (size_t)DMODEL * DMODEL * 2;
  ushort_t* Wout_bf  = (ushort_t*)(ws + off); off += (size_t)DMODEL * DMODEL * 2;
  float*    chunkA   = (float*)(ws + off);    off += (size_t)B_ * NH * NC * 4;
  ushort_t* BT_g     = (ushort_t*)(ws + off); off += (size_t)B_ * NC * NSTATE * CLEN * 2;
  ushort_t* ybuf_bf  = hbcdt_bf;                       // alias (hBC_dt dead)

  char* outc = (char*)d_out;
  ushort_t* gate_bf = (ushort_t*)outc;                              // 33.5 MB
  ushort_t* hs_bf   = (ushort_t*)(outc + (size_t)ROWS * INTER * 2); // 33.5 MB
  ushort_t* Sbuf    = hs_bf;   // states overwrite hs_bf after GEMMs consume it

  // 0. conversions
  cvt_f32_bf16<<<(ROWS * DMODEL / 4 + 255) / 256, 256, 0, stream>>>(
      hs, hs_bf, ROWS * DMODEL);
  cvt_Wh<<<(WH_ROWS * DMODEL / 4 + 255) / 256, 256, 0, stream>>>(W_in, Wh_bf);
  cvt_f32_bf16<<<(DMODEL * DMODEL / 4 + 255) / 256, 256, 0, stream>>>(
      W_in, Wg_bf, DMODEL * DMODEL);
  cvt_f32_bf16<<<(DMODEL * DMODEL / 4 + 255) / 256, 256, 0, stream>>>(
      W_out, Wout_bf, DMODEL * DMODEL);

  // 1a. hBC_dt = hs @ Wh^T  (320-wide tiles: 32x8 = 256 wg, no tail;
  //     stores guarded to 2432)
  gemm320_nt<8, HBCDT_PAD, HBCDT_PAD><<<dim3(8, 32), 512, 0, stream>>>(
      hs_bf, Wh_bf, hbcdt_bf);
  // 1b. gate = hs @ Wg^T
  gemm256_nt<true, 8, INTER, INTER><<<dim3(8, 32), 512, 0, stream>>>(
      hs_bf, Wg_bf, gate_bf);
  // 2. conv + silu (+ transposed B copy for scan-state MFMA)
  conv_silu_kernel<<<(ROWS * CONV_DIM + 255) / 256, 256, 0, stream>>>(
      hbcdt_bf, conv_w, conv_b, convo, BT_g);
  // 3. dt
  dtprep_kernel<<<(ROWS * NH + 255) / 256, 256, 0, stream>>>(
      hbcdt_bf, dt_bias, dt_s);
  // 4. chunked scan: MFMA local states -> combine -> SSD Y (MFMA)
  scan_state_kernel<<<B_ * NH * NC, 256, 0, stream>>>(
      convo, dt_s, A_log, BT_g, Sbuf, chunkA);
  state_combine_kernel<<<(B_ * NH * PDIM * (NSTATE / 4)) / 256, 256, 0, stream>>>(
      Sbuf, chunkA);
  ssd_y_kernel<<<B_ * NH * NC, 256, 0, stream>>>(
      convo, dt_s, A_log, D_param, Sbuf, ybuf_bf);
  // 5. gated rmsnorm (in-place on ybuf_bf)
  gated_rmsnorm_kernel<<<ROWS, 256, 0, stream>>>(ybuf_bf, gate_bf, norm_w);
  // 6. out = g @ W_out^T (fp32, overwrites d_out)
  gemm256_nt<false, 8, DMODEL, DMODEL><<<dim3(8, 32), 512, 0, stream>>>(
      ybuf_bf, Wout_bf, out);
}

// Round 7
// 587.148 us; speedup vs baseline: 1.1013x; 1.0127x over previous
//
#include <hip/hip_runtime.h>
#include <cstdint>
#include <cstddef>

// Problem constants
#define B_        2
#define LSEQ      4096
#define DMODEL    2048
#define NH        32
#define PDIM      64
#define NSTATE    128
#define KCONV     4
#define INTER     2048       // NH*PDIM
#define CONV_DIM  2304       // INTER + 2*NSTATE
#define HBCDT     2336       // CONV_DIM + NH
#define HBCDT_PAD 2432       // hbcdt row stride (19*128), unchanged
#define WH_ROWS   2560       // W_h padded rows (= 8 tiles of 320)
#define ROWS      (B_*LSEQ)  // 8192
#define NC        32         // sequence chunks for the scan
#define CLEN      (LSEQ/NC)  // 128  (= Q)

typedef unsigned short ushort_t;
typedef short bf16x8 __attribute__((ext_vector_type(8)));
typedef float f32x4 __attribute__((ext_vector_type(4)));

__device__ __forceinline__ float siluf(float x) {
  return x / (1.0f + __expf(-x));
}
__device__ __forceinline__ float bf2f(ushort_t u) {
  union { unsigned int i; float f; } v; v.i = ((unsigned int)u) << 16; return v.f;
}
__device__ __forceinline__ ushort_t f2bf(float f) {
  union { float f; unsigned int i; } v; v.f = f;
  unsigned int r = v.i + 0x7fff + ((v.i >> 16) & 1);   // RNE
  return (ushort_t)(r >> 16);
}
__device__ __forceinline__ void async16(const void* g, void* l) {
  __builtin_amdgcn_global_load_lds(
      (const __attribute__((address_space(1))) unsigned int*)g,
      (__attribute__((address_space(3))) unsigned int*)l, 16, 0, 0);
}

// ---------------------------------------------------------------------------
// fp32 -> bf16 conversions
// ---------------------------------------------------------------------------
__global__ __launch_bounds__(256) void cvt_f32_bf16(
    const float* __restrict__ src, ushort_t* __restrict__ dst, int n) {
  const int i = (blockIdx.x * 256 + threadIdx.x) * 4;
  if (i >= n) return;
  float4 v = *(const float4*)(src + i);
  ushort4 o; o.x = f2bf(v.x); o.y = f2bf(v.y); o.z = f2bf(v.z); o.w = f2bf(v.w);
  *(ushort4*)(dst + i) = o;
}

// W_in rows [INTER, INTER+HBCDT) -> bf16 padded to WH_ROWS rows (zeros)
__global__ __launch_bounds__(256) void cvt_Wh(
    const float* __restrict__ W_in, ushort_t* __restrict__ dst) {
  const int i = (blockIdx.x * 256 + threadIdx.x) * 4;
  if (i >= WH_ROWS * DMODEL) return;
  const int r = i / DMODEL, c = i % DMODEL;
  ushort4 o;
  if (r < HBCDT) {
    float4 v = *(const float4*)(W_in + (size_t)(INTER + r) * DMODEL + c);
    o.x = f2bf(v.x); o.y = f2bf(v.y); o.z = f2bf(v.z); o.w = f2bf(v.w);
  } else {
    o.x = 0; o.y = 0; o.z = 0; o.w = 0;
  }
  *(ushort4*)(dst + i) = o;
}

// ---------------------------------------------------------------------------
// Shared GEMM building blocks (bf16 NT, BK=64, 8 waves, counted vmcnt,
// T2 LDS granule swizzle via pre-swizzled global src, T5 setprio, T1 XCD
// bid swizzle). Two tile variants:
//   gemm256_nt: 256x256 tile (LDS 128 KiB), for N = 2048 launches (256 wg).
//   gemm320_nt: 256x320 tile (LDS 144 KiB), for N = 2560 (1a) -> exactly
//               256 wg = one full dispatch round, no tail.
// ---------------------------------------------------------------------------
#define STAGE_A(CN, H, KTT) do {                                              \
    async16(Ast + (size_t)((H) * 128) * 2048 + (KTT) * 64,                    \
            smem_ + (CN) + (H) * 16384 + wave * 1024);                        \
    async16(Ast + (size_t)((H) * 128 + 64) * 2048 + (KTT) * 64,               \
            smem_ + (CN) + (H) * 16384 + 8192 + wave * 1024);                 \
  } while (0)

#define STAGE_B(CN, H, KTT) do {                                              \
    async16(Bst + (size_t)((H) * 128) * 2048 + (KTT) * 64,                    \
            smem_ + 65536 + (CN) + (H) * 16384 + wave * 1024);                \
    async16(Bst + (size_t)((H) * 128 + 64) * 2048 + (KTT) * 64,               \
            smem_ + 65536 + (CN) + (H) * 16384 + 8192 + wave * 1024);         \
  } while (0)

#define LDA(DST, CB, MH) do {                                                 \
    const char* ab_ = smem_ + (CB) + aro;                                     \
    _Pragma("unroll") for (int mi_ = 0; mi_ < 4; ++mi_) {                     \
      DST[mi_][0] = *(const bf16x8*)(ab_ + (MH) * 8192 + mi_ * 2048 + g0);    \
      DST[mi_][1] = *(const bf16x8*)(ab_ + (MH) * 8192 + mi_ * 2048 + g1);    \
    }                                                                         \
  } while (0)

#define LDB(DST, CB, NHH) do {                                                \
    const char* bb_ = smem_ + 65536 + (CB) + bro;                             \
    _Pragma("unroll") for (int ni_ = 0; ni_ < 2; ++ni_) {                     \
      DST[ni_][0] = *(const bf16x8*)(bb_ + (NHH) * 4096 + ni_ * 2048 + g0);   \
      DST[ni_][1] = *(const bf16x8*)(bb_ + (NHH) * 4096 + ni_ * 2048 + g1);   \
    }                                                                         \
  } while (0)

#define MFMAQ(MH, NHH, AF, BF)                                                \
  _Pragma("unroll") for (int mi_ = 0; mi_ < 4; ++mi_)                         \
  _Pragma("unroll") for (int ni_ = 0; ni_ < 2; ++ni_) {                       \
    f32x4& c_ = acc[(MH) * 4 + mi_][(NHH) * 2 + ni_];                         \
    c_ = __builtin_amdgcn_mfma_f32_16x16x32_bf16(AF[mi_][0], BF[ni_][0], c_, 0, 0, 0); \
    c_ = __builtin_amdgcn_mfma_f32_16x16x32_bf16(AF[mi_][1], BF[ni_][1], c_, 0, 0, 0); \
  }

// Phase: barriers delimit the MFMA cluster; no forced lgkmcnt drain --
// register data-deps make the compiler emit minimal per-operand waits.
#define PH(X) do {                                                            \
    __builtin_amdgcn_s_barrier();                                             \
    __builtin_amdgcn_s_setprio(1);                                            \
    X;                                                                        \
    __builtin_amdgcn_s_setprio(0);                                            \
    __builtin_amdgcn_s_barrier();                                             \
  } while (0)

#define GROUP_TAIL_CNT(X, DOSTAGE, CN, KTT) do {                              \
    __builtin_amdgcn_s_barrier();                                             \
    __builtin_amdgcn_s_setprio(1);                                            \
    X;                                                                        \
    __builtin_amdgcn_s_setprio(0);                                            \
    if (DOSTAGE) {                                                            \
      STAGE_A(CN, 0, KTT); STAGE_A(CN, 1, KTT);                               \
      STAGE_B(CN, 0, KTT); STAGE_B(CN, 1, KTT);                               \
      asm volatile("s_waitcnt vmcnt(8)" ::: "memory");                        \
    } else {                                                                  \
      asm volatile("s_waitcnt vmcnt(0)" ::: "memory");                        \
    }                                                                         \
    __builtin_amdgcn_s_barrier();                                             \
  } while (0)

template <bool OUT_BF16, int NTN, int NVALID, int LDC>
__global__ __launch_bounds__(512, 2) void gemm256_nt(
    const ushort_t* __restrict__ A, const ushort_t* __restrict__ B,
    void* __restrict__ C) {
  __shared__ __align__(16) char smem_[131072];
  const int t    = threadIdx.x;
  const int lane = t & 63;
  const int wave = t >> 6;
  const int wm   = wave >> 2;   // 0..1  (M half of the tile)
  const int wn   = wave & 3;    // 0..3  (N quarter)

  // XCD-aware tile swizzle (NWG % 8 == 0 always here -> bijective)
  constexpr int NWG = NTN * 32;
  int bid = blockIdx.y * NTN + blockIdx.x;
  bid = (bid & 7) * (NWG >> 3) + (bid >> 3);
  const int m0 = (bid / NTN) * 256;
  const int n0 = (bid % NTN) * 256;

  // staging: thread covers row (wave*8 + lane>>3), granule (lane&7)^(lane>>3)
  const int srow = wave * 8 + (lane >> 3);
  const int scol = ((lane & 7) ^ (lane >> 3)) * 8;
  const ushort_t* Ast = A + (size_t)(m0 + srow) * 2048 + scol;
  const ushort_t* Bst = B + (size_t)(n0 + srow) * 2048 + scol;

  // fragment-read bases; row&7 == lane&7 for all fragment rows
  const int aro = (wm * 128 + (lane & 15)) * 128;
  const int bro = (wn * 64 + (lane & 15)) * 128;
  const int g0  = ((lane >> 4) ^ (lane & 7)) * 16;
  const int g1  = (((lane >> 4) + 4) ^ (lane & 7)) * 16;

  f32x4 acc[8][4];
#pragma unroll
  for (int i = 0; i < 8; ++i)
#pragma unroll
    for (int j = 0; j < 4; ++j) {
      f32x4 z = {0.f, 0.f, 0.f, 0.f};
      acc[i][j] = z;
    }
  bf16x8 af[4][2], bq0[2][2], bq1[2][2];

  // prologue: stage tile 0 -> buf0, tile 1 -> buf1; wait only for tile 0
  STAGE_A(0, 0, 0); STAGE_A(0, 1, 0);
  STAGE_B(0, 0, 0); STAGE_B(0, 1, 0);
  STAGE_A(32768, 0, 1); STAGE_A(32768, 1, 1);
  STAGE_B(32768, 0, 1); STAGE_B(32768, 1, 1);
  asm volatile("s_waitcnt vmcnt(8)" ::: "memory");
  __builtin_amdgcn_s_barrier();

  constexpr int NT = 2048 / 64;  // 32 K-tiles
  for (int kt = 0; kt < NT; kt += 2) {
    // ---- group A: compute tile kt from buf0; tail stages kt+2 -> buf0 ----
    LDA(af, 0, 0); LDB(bq0, 0, 0);
    PH(MFMAQ(0, 0, af, bq0));
    LDB(bq1, 0, 1);
    PH(MFMAQ(0, 1, af, bq1));
    LDA(af, 0, 1);                       // bq0/bq1 stay live -- no re-reads
    PH(MFMAQ(1, 0, af, bq0));
    GROUP_TAIL_CNT(MFMAQ(1, 1, af, bq1), (kt + 2) < NT, 0, kt + 2);
    // ---- group B: compute tile kt+1 from buf1; tail stages kt+3 -> buf1 ----
    LDA(af, 32768, 0); LDB(bq0, 32768, 0);
    PH(MFMAQ(0, 0, af, bq0));
    LDB(bq1, 32768, 1);
    PH(MFMAQ(0, 1, af, bq1));
    LDA(af, 32768, 1);
    PH(MFMAQ(1, 0, af, bq0));
    GROUP_TAIL_CNT(MFMAQ(1, 1, af, bq1), (kt + 3) < NT, 32768, kt + 3);
  }

  // epilogue: C/D mapping col=lane&15, row=(lane>>4)*4+reg
  const int mb = m0 + wm * 128 + (lane >> 4) * 4;
  const int nb = n0 + wn * 64 + (lane & 15);
#pragma unroll
  for (int mq = 0; mq < 8; ++mq)
#pragma unroll
    for (int nq = 0; nq < 4; ++nq)
#pragma unroll
      for (int r = 0; r < 4; ++r) {
        const int m = mb + mq * 16 + r;
        const int n = nb + nq * 16;
        if (n < NVALID) {
          if (OUT_BF16)
            ((ushort_t*)C)[(size_t)m * LDC + n] = f2bf(acc[mq][nq][r]);
          else
            ((float*)C)[(size_t)m * LDC + n] = acc[mq][nq][r];
        }
      }
}

// ---------------------------------------------------------------------------
// 256x320-tile variant (1a only): N = 2560 = 8 tiles -> grid 32x8 = 256 wg,
// exactly one dispatch round (no tail). Per-wave output 128x80 (acc[8][5]).
// LDS 144 KiB: A[2][256][64] @ {0,32768}; B[2][320][64] @ 65536+{0,40960}.
// Staging 9 async16/wave/tile (A:4, B:5, 64-row units); tail vmcnt(9).
// Phases per K-tile: MFMA 24/16/24/16 (n-groups 3+2 per M-half).
// ---------------------------------------------------------------------------
#define ST_A64(CN, HB, KTT)                                                   \
    async16(Ast + (size_t)((HB) * 64) * 2048 + (KTT) * 64,                    \
            smem_ + (CN) + (HB) * 8192 + wave * 1024)
#define ST_B64(CN, HB, KTT)                                                   \
    async16(Bst + (size_t)((HB) * 64) * 2048 + (KTT) * 64,                    \
            smem_ + 65536 + (CN) + (HB) * 8192 + wave * 1024)
#define STAGE9(ACN, BCN, KTT) do {                                            \
    ST_A64(ACN, 0, KTT); ST_A64(ACN, 1, KTT);                                 \
    ST_A64(ACN, 2, KTT); ST_A64(ACN, 3, KTT);                                 \
    ST_B64(BCN, 0, KTT); ST_B64(BCN, 1, KTT); ST_B64(BCN, 2, KTT);            \
    ST_B64(BCN, 3, KTT); ST_B64(BCN, 4, KTT);                                 \
  } while (0)

#define LDB3(DST, BCN) do {                                                   \
    const char* bb_ = smem_ + 65536 + (BCN) + bro;                            \
    _Pragma("unroll") for (int ni_ = 0; ni_ < 3; ++ni_) {                     \
      DST[ni_][0] = *(const bf16x8*)(bb_ + ni_ * 2048 + g0);                  \
      DST[ni_][1] = *(const bf16x8*)(bb_ + ni_ * 2048 + g1);                  \
    }                                                                         \
  } while (0)

#define LDB2(DST, BCN) do {                                                   \
    const char* bb_ = smem_ + 65536 + (BCN) + bro;                            \
    _Pragma("unroll") for (int ni_ = 0; ni_ < 2; ++ni_) {                     \
      DST[ni_][0] = *(const bf16x8*)(bb_ + (3 + ni_) * 2048 + g0);            \
      DST[ni_][1] = *(const bf16x8*)(bb_ + (3 + ni_) * 2048 + g1);            \
    }                                                                         \
  } while (0)

#define MFMA_G(MH, NB, NCNT, AF, BF)                                          \
  _Pragma("unroll") for (int mi_ = 0; mi_ < 4; ++mi_)                         \
  _Pragma("unroll") for (int ni_ = 0; ni_ < NCNT; ++ni_) {                    \
    f32x4& c_ = acc[(MH) * 4 + mi_][(NB) + ni_];                              \
    c_ = __builtin_amdgcn_mfma_f32_16x16x32_bf16(AF[mi_][0], BF[ni_][0], c_, 0, 0, 0); \
    c_ = __builtin_amdgcn_mfma_f32_16x16x32_bf16(AF[mi_][1], BF[ni_][1], c_, 0, 0, 0); \
  }

#define GROUP_TAIL9(X, DOSTAGE, ACN, BCN, KTT) do {                           \
    __builtin_amdgcn_s_barrier();                                             \
    __builtin_amdgcn_s_setprio(1);                                            \
    X;                                                                        \
    __builtin_amdgcn_s_setprio(0);                                            \
    if (DOSTAGE) {                                                            \
      STAGE9(ACN, BCN, KTT);                                                  \
      asm volatile("s_waitcnt vmcnt(9)" ::: "memory");                        \
    } else {                                                                  \
      asm volatile("s_waitcnt vmcnt(0)" ::: "memory");                        \
    }                                                                         \
    __builtin_amdgcn_s_barrier();                                             \
  } while (0)

template <int NTN, int NVALID, int LDC>
__global__ __launch_bounds__(512, 2) void gemm320_nt(
    const ushort_t* __restrict__ A, const ushort_t* __restrict__ B,
    ushort_t* __restrict__ C) {
  __shared__ __align__(16) char smem_[147456];
  const int t    = threadIdx.x;
  const int lane = t & 63;
  const int wave = t >> 6;
  const int wm   = wave >> 2;   // 0..1
  const int wn   = wave & 3;    // 0..3

  constexpr int NWG = NTN * 32;
  int bid = blockIdx.y * NTN + blockIdx.x;
  bid = (bid & 7) * (NWG >> 3) + (bid >> 3);
  const int m0 = (bid / NTN) * 256;
  const int n0 = (bid % NTN) * 320;

  const int srow = wave * 8 + (lane >> 3);
  const int scol = ((lane & 7) ^ (lane >> 3)) * 8;
  const ushort_t* Ast = A + (size_t)(m0 + srow) * 2048 + scol;
  const ushort_t* Bst = B + (size_t)(n0 + srow) * 2048 + scol;

  // fragment-read bases; all fragment rows are == lane&7 (mod 8): wm*128,
  // wn*80, mi*16, ni*16 are all 0 mod 8 (80 & 7 == 0).
  const int aro = (wm * 128 + (lane & 15)) * 128;
  const int bro = (wn * 80 + (lane & 15)) * 128;
  const int g0  = ((lane >> 4) ^ (lane & 7)) * 16;
  const int g1  = (((lane >> 4) + 4) ^ (lane & 7)) * 16;

  f32x4 acc[8][5];
#pragma unroll
  for (int i = 0; i < 8; ++i)
#pragma unroll
    for (int j = 0; j < 5; ++j) {
      f32x4 z = {0.f, 0.f, 0.f, 0.f};
      acc[i][j] = z;
    }
  bf16x8 af[4][2], bqA[3][2], bqB[2][2];

  // prologue: tile 0 -> buf0, tile 1 -> buf1; wait only for tile 0's 9
  STAGE9(0, 0, 0);
  STAGE9(32768, 40960, 1);
  asm volatile("s_waitcnt vmcnt(9)" ::: "memory");
  __builtin_amdgcn_s_barrier();

  constexpr int NT = 2048 / 64;  // 32 K-tiles
  for (int kt = 0; kt < NT; kt += 2) {
    // ---- tile kt from buf0; tail stages kt+2 -> buf0 ----
    LDA(af, 0, 0); LDB3(bqA, 0);
    PH(MFMA_G(0, 0, 3, af, bqA));
    LDB2(bqB, 0);
    PH(MFMA_G(0, 3, 2, af, bqB));
    LDA(af, 0, 1);                     // bqA/bqB stay live for M-half 1
    PH(MFMA_G(1, 0, 3, af, bqA));
    GROUP_TAIL9(MFMA_G(1, 3, 2, af, bqB), (kt + 2) < NT, 0, 0, kt + 2);
    // ---- tile kt+1 from buf1; tail stages kt+3 -> buf1 ----
    LDA(af, 32768, 0); LDB3(bqA, 40960);
    PH(MFMA_G(0, 0, 3, af, bqA));
    LDB2(bqB, 40960);
    PH(MFMA_G(0, 3, 2, af, bqB));
    LDA(af, 32768, 1);
    PH(MFMA_G(1, 0, 3, af, bqA));
    GROUP_TAIL9(MFMA_G(1, 3, 2, af, bqB), (kt + 3) < NT, 32768, 40960, kt + 3);
  }

  // epilogue
  const int mb = m0 + wm * 128 + (lane >> 4) * 4;
  const int nb = n0 + wn * 80 + (lane & 15);
#pragma unroll
  for (int mq = 0; mq < 8; ++mq)
#pragma unroll
    for (int nq = 0; nq < 5; ++nq)
#pragma unroll
      for (int r = 0; r < 4; ++r) {
        const int m = mb + mq * 16 + r;
        const int n = nb + nq * 16;
        if (n < NVALID)
          C[(size_t)m * LDC + n] = f2bf(acc[mq][nq][r]);
      }
}

// ---------------------------------------------------------------------------
// Depthwise causal conv1d (K=4) + bias + SiLU, VECTORIZED x8 (G13): each
// thread computes 8 consecutive channels -- 16B loads per tap instead of 8
// scalar ushort loads (scalar bf16 was the 94 us / 1.38 TB/s bottleneck).
// Input hbcdt bf16 (ld 2432), output convo bf16 (ld 2304). The B section
// (c in [INTER, INTER+NSTATE), 8-aligned) is additionally written
// transposed into BT_g[b][chunk][n][s_local] for the scan-state MFMA.
// ---------------------------------------------------------------------------
#define NC8 (CONV_DIM / 8)   // 288 channel-octets per row
__global__ __launch_bounds__(256) void conv_silu_kernel(
    const ushort_t* __restrict__ hbcdt, const float* __restrict__ conv_w,
    const float* __restrict__ conv_b, ushort_t* __restrict__ convo,
    ushort_t* __restrict__ BT_g) {
  const int idx = blockIdx.x * 256 + threadIdx.x;
  if (idx >= ROWS * NC8) return;
  const int c0  = (idx % NC8) * 8;
  const int row = idx / NC8;
  const int l   = row & (LSEQ - 1);

  // weights for 8 channels (conv_w is 36 KB -> L1-resident)
  float4 wv[8];
#pragma unroll
  for (int j = 0; j < 8; ++j)
    wv[j] = *(const float4*)(conv_w + (c0 + j) * KCONV);

  float acc[8];
  {
    float4 b0 = *(const float4*)(conv_b + c0);
    float4 b1 = *(const float4*)(conv_b + c0 + 4);
    acc[0] = b0.x; acc[1] = b0.y; acc[2] = b0.z; acc[3] = b0.w;
    acc[4] = b1.x; acc[5] = b1.y; acc[6] = b1.z; acc[7] = b1.w;
  }

#pragma unroll
  for (int k = 0; k < KCONV; ++k) {
    if (l + k >= KCONV - 1) {
      const ushort_t* src = hbcdt + (size_t)(row + k - (KCONV - 1)) * HBCDT_PAD + c0;
      ushort4 v0 = *(const ushort4*)src;
      ushort4 v1 = *(const ushort4*)(src + 4);
      acc[0] = fmaf(bf2f(v0.x), ((const float*)&wv[0])[k], acc[0]);
      acc[1] = fmaf(bf2f(v0.y), ((const float*)&wv[1])[k], acc[1]);
      acc[2] = fmaf(bf2f(v0.z), ((const float*)&wv[2])[k], acc[2]);
      acc[3] = fmaf(bf2f(v0.w), ((const float*)&wv[3])[k], acc[3]);
      acc[4] = fmaf(bf2f(v1.x), ((const float*)&wv[4])[k], acc[4]);
      acc[5] = fmaf(bf2f(v1.y), ((const float*)&wv[5])[k], acc[5]);
      acc[6] = fmaf(bf2f(v1.z), ((const float*)&wv[6])[k], acc[6]);
      acc[7] = fmaf(bf2f(v1.w), ((const float*)&wv[7])[k], acc[7]);
    }
  }

  ushort_t o[8];
#pragma unroll
  for (int j = 0; j < 8; ++j) o[j] = f2bf(siluf(acc[j]));

  ushort4 o0, o1;
  o0.x = o[0]; o0.y = o[1]; o0.z = o[2]; o0.w = o[3];
  o1.x = o[4]; o1.y = o[5]; o1.z = o[6]; o1.w = o[7];
  ushort_t* dst = convo + (size_t)row * CONV_DIM + c0;
  *(ushort4*)dst       = o0;
  *(ushort4*)(dst + 4) = o1;

  // transposed B copy (channel octet fully inside [INTER, INTER+NSTATE))
  if (c0 >= INTER && c0 < INTER + NSTATE) {
    const int bb  = row >> 12;        // / LSEQ
    const int cch = l >> 7;           // / CLEN
    const int sl  = l & (CLEN - 1);
    ushort_t* bt = BT_g + (((size_t)bb * NC + cch) * NSTATE + (c0 - INTER)) * CLEN + sl;
#pragma unroll
    for (int j = 0; j < 8; ++j) bt[(size_t)j * CLEN] = o[j];
  }
}

// ---------------------------------------------------------------------------
// dt = softplus(dt_raw + dt_bias)
// ---------------------------------------------------------------------------
__global__ __launch_bounds__(256) void dtprep_kernel(
    const ushort_t* __restrict__ hbcdt, const float* __restrict__ dt_bias,
    float* __restrict__ dt_s) {
  const int idx = blockIdx.x * 256 + threadIdx.x;
  if (idx >= ROWS * NH) return;
  const int h   = idx & (NH - 1);
  const int row = idx >> 5;
  float x = bf2f(hbcdt[(size_t)row * HBCDT_PAD + CONV_DIM + h]) + dt_bias[h];
  dt_s[idx] = (x > 20.f) ? x : log1pf(__expf(x));
}

// ---------------------------------------------------------------------------
// Chunked scan, pass 1 (MFMA form): per (b,h,c),
//   La = cumsum(-exp(A_log[h])*dt);  wgt[s] = dt_s * exp(La_end - La_s)
//   S_loc[p][n] = sum_s (x_s[p]*wgt[s]) * B_s[n]   -> NT MFMA, K=s=128
//   chunkA = exp(La_end)
// Grid: B*NH*NC = 2048 blocks x 256 thr (4 waves; wave w -> p rows w*16..+16).
// ---------------------------------------------------------------------------
#define XLD 272   // Xw^T row stride bytes (128*2 + 16 pad -> 2-way conflicts only)
__global__ __launch_bounds__(256) void scan_state_kernel(
    const ushort_t* __restrict__ convo, const float* __restrict__ dt_s,
    const float* __restrict__ A_log, const ushort_t* __restrict__ BT_g,
    ushort_t* __restrict__ Sbuf, float* __restrict__ chunkA) {
  __shared__ __align__(16) char XwT[64 * XLD];   // [p][s] bf16, weighted
  __shared__ float dt_sh[CLEN];
  __shared__ float wgt[CLEN];

  const int blk = blockIdx.x;
  const int c   = blk & (NC - 1);
  const int h   = (blk >> 5) & 31;
  const int b   = blk >> 10;
  const int t   = threadIdx.x;
  const int lane = t & 63;
  const int wave = t >> 6;
  const size_t crow = (size_t)(b * LSEQ + c * CLEN);

  if (t < CLEN) dt_sh[t] = dt_s[(crow + t) * NH + h];
  __syncthreads();

  if (wave == 0) {
    const float a = __expf(A_log[h]);
    float v0 = -a * dt_sh[lane];
    float v1 = -a * dt_sh[lane + 64];
#pragma unroll
    for (int off = 1; off < 64; off <<= 1) {
      float u0 = __shfl_up(v0, off);
      float u1 = __shfl_up(v1, off);
      if (lane >= off) { v0 += u0; v1 += u1; }
    }
    const float tot0 = __shfl(v0, 63);
    const float La0  = v0;
    const float La1  = v1 + tot0;
    const float Lend = __shfl(v1, 63) + tot0;
    wgt[lane]      = dt_sh[lane]      * __expf(Lend - La0);
    wgt[lane + 64] = dt_sh[lane + 64] * __expf(Lend - La1);
    if (lane == 0) chunkA[(b * NH + h) * NC + c] = __expf(Lend);
  }
  __syncthreads();

  // stage weighted Xw^T: thread lane = p, wave covers t in [wave*32, +32)
  {
    const int p = lane;
    const int xcol = h * PDIM + p;
#pragma unroll
    for (int oct = 0; oct < 4; ++oct) {
      const int t0 = wave * 32 + oct * 8;
      unsigned int pk[4];
#pragma unroll
      for (int e = 0; e < 4; ++e) {
        const float f0 = bf2f(convo[(crow + t0 + 2*e)     * CONV_DIM + xcol]) * wgt[t0 + 2*e];
        const float f1 = bf2f(convo[(crow + t0 + 2*e + 1) * CONV_DIM + xcol]) * wgt[t0 + 2*e + 1];
        pk[e] = (unsigned int)f2bf(f0) | ((unsigned int)f2bf(f1) << 16);
      }
      *(uint4*)(XwT + p * XLD + t0 * 2) = make_uint4(pk[0], pk[1], pk[2], pk[3]);
    }
  }
  __syncthreads();

  // MFMA: S_loc[p][n], A = Xw^T (LDS), B = BT_g (global, L2-hot)
  f32x4 acc[8];
#pragma unroll
  for (int j = 0; j < 8; ++j) {
    f32x4 z = {0.f, 0.f, 0.f, 0.f};
    acc[j] = z;
  }
  const int rowA = wave * 16 + (lane & 15);
  const int koff = (lane >> 4) * 8;
  const ushort_t* Bt = BT_g + ((size_t)b * NC + c) * NSTATE * CLEN;
#pragma unroll
  for (int k0 = 0; k0 < 4; ++k0) {
    bf16x8 af = *(const bf16x8*)(XwT + rowA * XLD + (k0 * 32 + koff) * 2);
#pragma unroll
    for (int j = 0; j < 8; ++j) {
      bf16x8 bfx = *(const bf16x8*)(Bt + (size_t)(j * 16 + (lane & 15)) * CLEN + k0 * 32 + koff);
      acc[j] = __builtin_amdgcn_mfma_f32_16x16x32_bf16(af, bfx, acc[j], 0, 0, 0);
    }
  }

  ushort_t* Sb = Sbuf + (((size_t)b * NC + c) * NH + h) * (PDIM * NSTATE);
  const int prow = wave * 16 + (lane >> 4) * 4;
  const int ncol = lane & 15;
#pragma unroll
  for (int j = 0; j < 8; ++j)
#pragma unroll
    for (int r = 0; r < 4; ++r)
      Sb[(size_t)(prow + r) * NSTATE + j * 16 + ncol] = f2bf(acc[j][r]);
}

// ---------------------------------------------------------------------------
// Chunked scan, pass 2: in-place serial combine over chunks.
// ---------------------------------------------------------------------------
__global__ __launch_bounds__(256) void state_combine_kernel(
    ushort_t* __restrict__ Sbuf, const float* __restrict__ chunkA) {
  const int idx = blockIdx.x * 256 + threadIdx.x;
  const int nq = idx & 31;
  const int p  = (idx >> 5) & 63;
  const int h  = (idx >> 11) & 31;
  const int b  = (idx >> 16) & 1;
  const float* ca = chunkA + (b * NH + h) * NC;

  float s0 = 0.f, s1 = 0.f, s2 = 0.f, s3 = 0.f;
#pragma unroll 4
  for (int c = 0; c < NC; ++c) {
    const size_t off = ((((size_t)b * NC + c) * NH + h) * PDIM + p) * NSTATE + nq * 4;
    ushort4 loc = *(const ushort4*)(Sbuf + off);
    ushort4 o;
    o.x = f2bf(s0); o.y = f2bf(s1); o.z = f2bf(s2); o.w = f2bf(s3);
    *(ushort4*)(Sbuf + off) = o;                 // Sin for chunk c
    const float a = ca[c];
    s0 = fmaf(a, s0, bf2f(loc.x));
    s1 = fmaf(a, s1, bf2f(loc.y));
    s2 = fmaf(a, s2, bf2f(loc.z));
    s3 = fmaf(a, s3, bf2f(loc.w));
  }
}

// ---------------------------------------------------------------------------
// SSD Y-kernel: per (b,h,c) chunk of Q=128,
//   La[t] = cumsum(-exp(A_log[h])*dt) over chunk
//   G = C @ B^T;  W[t,s] = (t>=s) ? G*dt[s]*exp(La[t]-La[s]) : 0  -> LDS bf16
//   Y = exp(La[t]) o (C @ Sin^T) + W @ X + D*x
// Grid: B*NH*NC = 2048 blocks x 256 thr (4 waves).
// ---------------------------------------------------------------------------
#define WLD 272   // W row stride bytes (128*2 + 16 pad -> 2-way bank conflicts only)
__global__ __launch_bounds__(256) void ssd_y_kernel(
    const ushort_t* __restrict__ convo, const float* __restrict__ dt_s,
    const float* __restrict__ A_log, const float* __restrict__ D_param,
    const ushort_t* __restrict__ Sbuf, ushort_t* __restrict__ ybuf) {
  __shared__ __align__(16) char XT[64 * 256];     // [p][t^sw] bf16
  __shared__ __align__(16) char Wsh[128 * WLD];   // [t][s] bf16, padded rows
  __shared__ float dt_sh[CLEN];
  __shared__ float La[CLEN];

  const int blk = blockIdx.x;
  const int c   = blk & (NC - 1);
  const int h   = (blk >> 5) & 31;
  const int b   = blk >> 10;
  const int t   = threadIdx.x;
  const int lane = t & 63;
  const int wave = t >> 6;

  const size_t crow = (size_t)(b * LSEQ + c * CLEN);

  // ---- stage X transposed into LDS (XOR swizzle on t within 64-t octets) ----
  {
    const int p = lane;
    const int xcol = h * PDIM + p;
#pragma unroll
    for (int oct = 0; oct < 4; ++oct) {
      const int tl0 = wave * 32 + oct * 8;
      unsigned int pk[4];
#pragma unroll
      for (int e = 0; e < 4; ++e) {
        ushort_t v0 = convo[(crow + tl0 + 2 * e) * CONV_DIM + xcol];
        ushort_t v1 = convo[(crow + tl0 + 2 * e + 1) * CONV_DIM + xcol];
        pk[e] = (unsigned int)v0 | ((unsigned int)v1 << 16);
      }
      const int tsw = tl0 ^ ((p & 7) << 3);
      *(uint4*)(XT + p * 256 + tsw * 2) = make_uint4(pk[0], pk[1], pk[2], pk[3]);
    }
  }
  // ---- stage dt for chunk ----
  if (t < CLEN) dt_sh[t] = dt_s[(crow + t) * NH + h];
  __syncthreads();

  // ---- wave 0: inclusive prefix sum of log(dA) = -a*dt ----
  if (wave == 0) {
    const float a = __expf(A_log[h]);
    float v0 = -a * dt_sh[lane];
    float v1 = -a * dt_sh[lane + 64];
#pragma unroll
    for (int off = 1; off < 64; off <<= 1) {
      float u0 = __shfl_up(v0, off);
      float u1 = __shfl_up(v1, off);
      if (lane >= off) { v0 += u0; v1 += u1; }
    }
    const float tot0 = __shfl(v0, 63);
    La[lane]      = v0;
    La[lane + 64] = v1 + tot0;
  }
  __syncthreads();

  // ---- phase 1: G = C @ B^T (per-wave 64x64 tile), then W -> LDS ----
  const int wt = wave & 1;
  const int ws = wave >> 1;
  const bool active = !(wt == 0 && ws == 1);   // strictly-upper tile is all zero

  f32x4 g[4][4];
#pragma unroll
  for (int i = 0; i < 4; ++i)
#pragma unroll
    for (int j = 0; j < 4; ++j) {
      f32x4 z = {0.f, 0.f, 0.f, 0.f};
      g[i][j] = z;
    }

  if (active) {
    for (int k0 = 0; k0 < 4; ++k0) {
      const int koct = k0 * 32 + (lane >> 4) * 8;
      bf16x8 cf[4], bfg[4];
#pragma unroll
      for (int i = 0; i < 4; ++i) {
        const int tg = wt * 64 + i * 16 + (lane & 15);
        cf[i] = *(const bf16x8*)(convo + (crow + tg) * CONV_DIM + INTER + NSTATE + koct);
        const int sg = ws * 64 + i * 16 + (lane & 15);
        bfg[i] = *(const bf16x8*)(convo + (crow + sg) * CONV_DIM + INTER + koct);
      }
#pragma unroll
      for (int i = 0; i < 4; ++i)
#pragma unroll
        for (int j = 0; j < 4; ++j)
          g[i][j] = __builtin_amdgcn_mfma_f32_16x16x32_bf16(cf[i], bfg[j], g[i][j], 0, 0, 0);
    }
  }
#pragma unroll
  for (int i = 0; i < 4; ++i) {
    const int tbase = wt * 64 + i * 16 + ((lane >> 4) << 2);
    float Lat[4];
#pragma unroll
    for (int r = 0; r < 4; ++r) Lat[r] = La[tbase + r];
#pragma unroll
    for (int j = 0; j < 4; ++j) {
      const int sl  = ws * 64 + j * 16 + (lane & 15);
      const float Las = La[sl];
      const float dts = dt_sh[sl];
#pragma unroll
      for (int r = 0; r < 4; ++r) {
        const int tl = tbase + r;
        float val = 0.f;
        if (active && tl >= sl)
          val = g[i][j][r] * dts * __expf(Lat[r] - Las);
        *(ushort_t*)(Wsh + tl * WLD + sl * 2) = f2bf(val);
      }
    }
  }
  __syncthreads();

  // ---- phase 2: Y = exp(La) o (C @ Sin^T) + W @ X ----
  const int yt = wave & 1;        // t-half
  const int yp = wave >> 1;       // p-half (32 p's per wave)
  f32x4 acc[4][2];
#pragma unroll
  for (int i = 0; i < 4; ++i)
#pragma unroll
    for (int j = 0; j < 2; ++j) {
      f32x4 z = {0.f, 0.f, 0.f, 0.f};
      acc[i][j] = z;
    }

  const ushort_t* Sb = Sbuf + (((size_t)b * NC + c) * NH + h) * PDIM * NSTATE;

  // Yinter: C @ Sin^T  (K = N = 128)
  for (int k0 = 0; k0 < 4; ++k0) {
    const int koct = k0 * 32 + (lane >> 4) * 8;
    bf16x8 af[4], sf[2];
#pragma unroll
    for (int i = 0; i < 4; ++i) {
      const int tg = yt * 64 + i * 16 + (lane & 15);
      af[i] = *(const bf16x8*)(convo + (crow + tg) * CONV_DIM + INTER + NSTATE + koct);
    }
#pragma unroll
    for (int j = 0; j < 2; ++j) {
      const int pr = yp * 32 + j * 16 + (lane & 15);
      sf[j] = *(const bf16x8*)(Sb + pr * NSTATE + koct);
    }
#pragma unroll
    for (int i = 0; i < 4; ++i)
#pragma unroll
      for (int j = 0; j < 2; ++j)
        acc[i][j] = __builtin_amdgcn_mfma_f32_16x16x32_bf16(af[i], sf[j], acc[i][j], 0, 0, 0);
  }
  // scale by exp(La[t]) in fp32
#pragma unroll
  for (int i = 0; i < 4; ++i) {
    const int tbase = yt * 64 + i * 16 + ((lane >> 4) << 2);
#pragma unroll
    for (int r = 0; r < 4; ++r) {
      const float e = __expf(La[tbase + r]);
#pragma unroll
      for (int j = 0; j < 2; ++j) acc[i][j][r] *= e;
    }
  }
  // Yintra: W @ X  (K = Q = 128; A from Wsh, B from XT)
  for (int k0 = 0; k0 < 4; ++k0) {
    const int koct = k0 * 32 + (lane >> 4) * 8;
    bf16x8 wf[4], xf[2];
#pragma unroll
    for (int i = 0; i < 4; ++i) {
      const int tl = yt * 64 + i * 16 + (lane & 15);
      wf[i] = *(const bf16x8*)(Wsh + tl * WLD + koct * 2);
    }
#pragma unroll
    for (int j = 0; j < 2; ++j) {
      const int pr  = yp * 32 + j * 16 + (lane & 15);
      const int tsw = koct ^ ((pr & 7) << 3);
      xf[j] = *(const bf16x8*)(XT + pr * 256 + tsw * 2);
    }
#pragma unroll
    for (int i = 0; i < 4; ++i)
#pragma unroll
      for (int j = 0; j < 2; ++j)
        acc[i][j] = __builtin_amdgcn_mfma_f32_16x16x32_bf16(wf[i], xf[j], acc[i][j], 0, 0, 0);
  }

  // ---- epilogue: + D*x, write y ----
  const float Dh = D_param[h];
#pragma unroll
  for (int i = 0; i < 4; ++i) {
    const int tbase = yt * 64 + i * 16 + ((lane >> 4) << 2);
#pragma unroll
    for (int j = 0; j < 2; ++j) {
      const int pr = yp * 32 + j * 16 + (lane & 15);
#pragma unroll
      for (int r = 0; r < 4; ++r) {
        const int tl  = tbase + r;
        const int tsw = tl ^ ((pr & 7) << 3);
        const float x = bf2f(*(const ushort_t*)(XT + pr * 256 + tsw * 2));
        ybuf[(crow + tl) * INTER + h * PDIM + pr] = f2bf(acc[i][j][r] + Dh * x);
      }
    }
  }
}

// ---------------------------------------------------------------------------
// Gated RMSNorm (bf16 in/out, in-place on y).
// ---------------------------------------------------------------------------
__global__ __launch_bounds__(256) void gated_rmsnorm_kernel(
    ushort_t* __restrict__ y, const ushort_t* __restrict__ gate,
    const float* __restrict__ norm_w) {
  const int row = blockIdx.x;
  ushort_t* yr = y + (size_t)row * INTER;
  const ushort_t* gr = gate + (size_t)row * INTER;
  const int t  = threadIdx.x;
  const int i0 = t * 8;

  ushort4 ya = *(const ushort4*)(yr + i0);
  ushort4 yb = *(const ushort4*)(yr + i0 + 4);
  ushort4 ga = *(const ushort4*)(gr + i0);
  ushort4 gb = *(const ushort4*)(gr + i0 + 4);

  float g[8];
  g[0] = bf2f(ya.x) * siluf(bf2f(ga.x));
  g[1] = bf2f(ya.y) * siluf(bf2f(ga.y));
  g[2] = bf2f(ya.z) * siluf(bf2f(ga.z));
  g[3] = bf2f(ya.w) * siluf(bf2f(ga.w));
  g[4] = bf2f(yb.x) * siluf(bf2f(gb.x));
  g[5] = bf2f(yb.y) * siluf(bf2f(gb.y));
  g[6] = bf2f(yb.z) * siluf(bf2f(gb.z));
  g[7] = bf2f(yb.w) * siluf(bf2f(gb.w));

  float ss = 0.f;
#pragma unroll
  for (int i = 0; i < 8; ++i) ss += g[i] * g[i];

  ss += __shfl_xor(ss, 32);
  ss += __shfl_xor(ss, 16);
  ss += __shfl_xor(ss, 8);
  ss += __shfl_xor(ss, 4);
  ss += __shfl_xor(ss, 2);
  ss += __shfl_xor(ss, 1);

  __shared__ float red[4];
  if ((t & 63) == 0) red[t >> 6] = ss;
  __syncthreads();
  const float tot = red[0] + red[1] + red[2] + red[3];
  const float scale = rsqrtf(tot * (1.0f / INTER) + 1e-5f);

  ushort4 o0, o1;
  o0.x = f2bf(g[0] * scale * norm_w[i0 + 0]);
  o0.y = f2bf(g[1] * scale * norm_w[i0 + 1]);
  o0.z = f2bf(g[2] * scale * norm_w[i0 + 2]);
  o0.w = f2bf(g[3] * scale * norm_w[i0 + 3]);
  o1.x = f2bf(g[4] * scale * norm_w[i0 + 4]);
  o1.y = f2bf(g[5] * scale * norm_w[i0 + 5]);
  o1.z = f2bf(g[6] * scale * norm_w[i0 + 6]);
  o1.w = f2bf(g[7] * scale * norm_w[i0 + 7]);
  *(ushort4*)(yr + i0)     = o0;
  *(ushort4*)(yr + i0 + 4) = o1;
}

// ---------------------------------------------------------------------------
// Workspace (~108 MB): hbcdt_bf(39.8, aliased by ybuf) | convo(37.7) |
// dt_s(1) | Wh_bf(10.5, 2560 rows) | Wg_bf(8.4) | Wout_bf(8.4) | chunkA(8KB) |
// BT_g(2). d_out scratch: [0,33.5MB) gate_bf; [33.5,67MB) hs_bf -> Sbuf.
// ---------------------------------------------------------------------------
extern "C" void kernel_launch(void* const* d_in, const int* in_sizes, int n_in,
                              void* d_out, int out_size, void* d_ws, size_t ws_size,
                              hipStream_t stream) {
  const float* hs      = (const float*)d_in[0];
  const float* W_in    = (const float*)d_in[1];
  const float* conv_w  = (const float*)d_in[2];
  const float* conv_b  = (const float*)d_in[3];
  const float* dt_bias = (const float*)d_in[4];
  const float* A_log   = (const float*)d_in[5];
  const float* D_param = (const float*)d_in[6];
  const float* norm_w  = (const float*)d_in[7];
  const float* W_out   = (const float*)d_in[8];
  float* out = (float*)d_out;

  char* ws = (char*)d_ws;
  size_t off = 0;
  ushort_t* hbcdt_bf = (ushort_t*)(ws + off); off += (size_t)ROWS * HBCDT_PAD * 2;
  ushort_t* convo    = (ushort_t*)(ws + off); off += (size_t)ROWS * CONV_DIM * 2;
  float*    dt_s     = (float*)(ws + off);    off += (size_t)ROWS * NH * 4;
  ushort_t* Wh_bf    = (ushort_t*)(ws + off); off += (size_t)WH_ROWS * DMODEL * 2;
  ushort_t* Wg_bf    = (ushort_t*)(ws + off); off += (size_t)DMODEL * DMODEL * 2;
  ushort_t* Wout_bf  = (ushort_t*)(ws + off); off += (size_t)DMODEL * DMODEL * 2;
  float*    chunkA   = (float*)(ws + off);    off += (size_t)B_ * NH * NC * 4;
  ushort_t* BT_g     = (ushort_t*)(ws + off); off += (size_t)B_ * NC * NSTATE * CLEN * 2;
  ushort_t* ybuf_bf  = hbcdt_bf;                       // alias (hBC_dt dead)

  char* outc = (char*)d_out;
  ushort_t* gate_bf = (ushort_t*)outc;                              // 33.5 MB
  ushort_t* hs_bf   = (ushort_t*)(outc + (size_t)ROWS * INTER * 2); // 33.5 MB
  ushort_t* Sbuf    = hs_bf;   // states overwrite hs_bf after GEMMs consume it

  // 0. conversions
  cvt_f32_bf16<<<(ROWS * DMODEL / 4 + 255) / 256, 256, 0, stream>>>(
      hs, hs_bf, ROWS * DMODEL);
  cvt_Wh<<<(WH_ROWS * DMODEL / 4 + 255) / 256, 256, 0, stream>>>(W_in, Wh_bf);
  cvt_f32_bf16<<<(DMODEL * DMODEL / 4 + 255) / 256, 256, 0, stream>>>(
      W_in, Wg_bf, DMODEL * DMODEL);
  cvt_f32_bf16<<<(DMODEL * DMODEL / 4 + 255) / 256, 256, 0, stream>>>(
      W_out, Wout_bf, DMODEL * DMODEL);

  // 1a. hBC_dt = hs @ Wh^T  (320-wide tiles: 32x8 = 256 wg, no tail;
  //     stores guarded to 2432)
  gemm320_nt<8, HBCDT_PAD, HBCDT_PAD><<<dim3(8, 32), 512, 0, stream>>>(
      hs_bf, Wh_bf, hbcdt_bf);
  // 1b. gate = hs @ Wg^T
  gemm256_nt<true, 8, INTER, INTER><<<dim3(8, 32), 512, 0, stream>>>(
      hs_bf, Wg_bf, gate_bf);
  // 2. conv + silu (+ transposed B copy for scan-state MFMA), x8 vectorized
  conv_silu_kernel<<<(ROWS * NC8 + 255) / 256, 256, 0, stream>>>(
      hbcdt_bf, conv_w, conv_b, convo, BT_g);
  // 3. dt
  dtprep_kernel<<<(ROWS * NH + 255) / 256, 256, 0, stream>>>(
      hbcdt_bf, dt_bias, dt_s);
  // 4. chunked scan: MFMA local states -> combine -> SSD Y (MFMA)
  scan_state_kernel<<<B_ * NH * NC, 256, 0, stream>>>(
      convo, dt_s, A_log, BT_g, Sbuf, chunkA);
  state_combine_kernel<<<(B_ * NH * PDIM * (NSTATE / 4)) / 256, 256, 0, stream>>>(
      Sbuf, chunkA);
  ssd_y_kernel<<<B_ * NH * NC, 256, 0, stream>>>(
      convo, dt_s, A_log, D_param, Sbuf, ybuf_bf);
  // 5. gated rmsnorm (in-place on ybuf_bf)
  gated_rmsnorm_kernel<<<ROWS, 256, 0, stream>>>(ybuf_bf, gate_bf, norm_w);
  // 6. out = g @ W_out^T (fp32, overwrites d_out)
  gemm256_nt<false, 8, DMODEL, DMODEL><<<dim3(8, 32), 512, 0, stream>>>(
      ybuf_bf, Wout_bf, out);
}